// Round 1
// baseline (627.818 us; speedup 1.0000x reference)
//
#include <hip/hip_runtime.h>

#define NN 100000
#define NE 1250000

// ---------------- edge dtype detection (int32 vs int64) ----------------
__global__ __launch_bounds__(64) void detect_k(const int* __restrict__ e32, int* __restrict__ flag){
    int lane = threadIdx.x;
    int v = e32[2*lane + 1];                 // high word if int64, else a src value
    unsigned long long b = __ballot(v != 0);
    if(lane == 0) flag[0] = (b == 0ULL) ? 1 : 0;   // 1 => int64 layout
}

// ---------------- degree count ----------------
__global__ __launch_bounds__(256) void count_k(const int* __restrict__ e32, const int* __restrict__ flag,
                                               int* __restrict__ cnt){
    int i = blockIdx.x*256 + threadIdx.x;
    if(i >= NE) return;
    int f = flag[0];
    int d = e32[f ? 2*(NE + i) : (NE + i)];
    atomicAdd(&cnt[d], 1);
}

__global__ __launch_bounds__(256) void dinv_k(const int* __restrict__ cnt, float* __restrict__ dinv){
    int i = blockIdx.x*256 + threadIdx.x;
    if(i < NN) dinv[i] = rsqrtf((float)(cnt[i] + 1));   // +1 = self loop
}

// ---------------- exclusive scan (3 kernels) ----------------
__global__ __launch_bounds__(256) void scan_a(const int* __restrict__ cnt, int* __restrict__ rp,
                                              int* __restrict__ bsums){
    __shared__ int s[256];
    int i = blockIdx.x*256 + threadIdx.x;
    int v = (i < NN) ? cnt[i] : 0;
    s[threadIdx.x] = v; __syncthreads();
    for(int off = 1; off < 256; off <<= 1){
        int t = (threadIdx.x >= off) ? s[threadIdx.x - off] : 0;
        __syncthreads();
        s[threadIdx.x] += t;
        __syncthreads();
    }
    if(i < NN) rp[i] = s[threadIdx.x] - v;          // exclusive
    if(threadIdx.x == 255) bsums[blockIdx.x] = s[255];
}

__global__ __launch_bounds__(512) void scan_b(int* __restrict__ bsums, int nb){
    __shared__ int s[512];
    int t = threadIdx.x;
    int v = (t < nb) ? bsums[t] : 0;
    s[t] = v; __syncthreads();
    for(int off = 1; off < 512; off <<= 1){
        int u = (t >= off) ? s[t - off] : 0;
        __syncthreads();
        s[t] += u;
        __syncthreads();
    }
    if(t < nb) bsums[t] = s[t] - v;                  // exclusive block offsets
}

__global__ __launch_bounds__(256) void scan_c(int* __restrict__ rp, const int* __restrict__ bsums,
                                              int* __restrict__ cursor){
    int i = blockIdx.x*256 + threadIdx.x;
    if(i < NN){
        int v = rp[i] + bsums[blockIdx.x];
        rp[i] = v;
        cursor[i] = v;
    }
    if(i == 0) rp[NN] = NE;
}

// ---------------- CSR fill ----------------
__global__ __launch_bounds__(256) void fill_k(const int* __restrict__ e32, const int* __restrict__ flag,
                                              int* __restrict__ cursor, const float* __restrict__ dinv,
                                              int* __restrict__ csr_src, float* __restrict__ csr_w){
    int i = blockIdx.x*256 + threadIdx.x;
    if(i >= NE) return;
    int f = flag[0];
    int s = e32[f ? 2*i        : i];
    int d = e32[f ? 2*(NE + i) : (NE + i)];
    int pos = atomicAdd(&cursor[d], 1);
    csr_src[pos] = s;
    csr_w[pos]   = dinv[s] * dinv[d];
}

// ---------------- dense GEMM: [M,K] @ [K,NC] -> [M,NC], optional relu on input ----------------
template<int K, int NC, bool RELU>
__global__ __launch_bounds__(256) void gemm_k(const float* __restrict__ A, const float* __restrict__ W,
                                              float* __restrict__ out, int M){
    constexpr int CH = K/4;          // float4 chunks per row
    constexpr int CMASK = CH - 1;
    __shared__ float Xs[64*K];
    __shared__ float Ws[K*NC];
    const int tid  = threadIdx.x;
    const int base = blockIdx.x * 64;

    for(int idx = tid; idx < K*NC; idx += 256) Ws[idx] = W[idx];

    for(int idx = tid; idx < 64*K; idx += 256){
        int r = idx / K;
        int k = idx % K;
        int row = base + r; if(row >= M) row = M - 1;
        float v = A[(size_t)row*K + k];
        if(RELU) v = fmaxf(v, 0.0f);
        int sw = ((k >> 2) + r) & CMASK;           // rotate-swizzle chunks to avoid bank conflicts
        Xs[r*K + (sw << 2) + (k & 3)] = v;
    }
    __syncthreads();

    const int tx = tid & 15, ty = tid >> 4;
    const int c0 = tx * 4;
    float acc[4][4] = {};
    if(c0 < NC){
        for(int k4 = 0; k4 < CH; ++k4){
            float4 xs[4];
            #pragma unroll
            for(int i = 0; i < 4; ++i){
                int r = ty*4 + i;
                int sw = (k4 + r) & CMASK;
                xs[i] = *(const float4*)&Xs[r*K + (sw << 2)];
            }
            float4 wsv[4];
            #pragma unroll
            for(int kk = 0; kk < 4; ++kk) wsv[kk] = *(const float4*)&Ws[(k4*4 + kk)*NC + c0];
            #pragma unroll
            for(int kk = 0; kk < 4; ++kk){
                const float* wp = (const float*)&wsv[kk];
                #pragma unroll
                for(int i = 0; i < 4; ++i){
                    float xv = ((const float*)&xs[i])[kk];
                    #pragma unroll
                    for(int j = 0; j < 4; ++j) acc[i][j] += xv * wp[j];
                }
            }
        }
    }
    #pragma unroll
    for(int i = 0; i < 4; ++i){
        int row = base + ty*4 + i;
        if(row < M && c0 < NC){
            float4 o; o.x = acc[i][0]; o.y = acc[i][1]; o.z = acc[i][2]; o.w = acc[i][3];
            *(float4*)&out[(size_t)row*NC + c0] = o;
        }
    }
}

// ---------------- CSR aggregation: G[v] = b + sum_{s in N(v)} H[s]*w + H[v]*dinv[v]^2 ----------------
template<int F>
__global__ __launch_bounds__(256) void agg_k(const float* __restrict__ H, const int* __restrict__ rp,
                                             const int* __restrict__ csr_src, const float* __restrict__ csr_w,
                                             const float* __restrict__ dinv, const float* __restrict__ bias,
                                             float* __restrict__ G){
    int lane = threadIdx.x & 63;
    int v = (blockIdx.x*256 + threadIdx.x) >> 6;
    if(v >= NN) return;
    float d = dinv[v];
    int beg = rp[v], end = rp[v + 1];
    float acc = 0.0f;
    if(lane < F) acc = bias[lane] + H[v*F + lane] * d * d;
    for(int j = beg; j < end; ++j){
        int s   = csr_src[j];
        float w = csr_w[j];
        if(lane < F) acc += H[s*F + lane] * w;
    }
    if(lane < F) G[v*F + lane] = acc;
}

// ---------------- in-place log_softmax over 40 channels, one wave per row ----------------
__global__ __launch_bounds__(256) void lsm_k(float* __restrict__ io){
    int lane = threadIdx.x & 63;
    int v = (blockIdx.x*256 + threadIdx.x) >> 6;
    if(v >= NN) return;
    float val = (lane < 40) ? io[v*40 + lane] : -3.402823466e38f;
    float m = val;
    #pragma unroll
    for(int off = 32; off; off >>= 1) m = fmaxf(m, __shfl_xor(m, off, 64));
    float e = (lane < 40) ? __expf(val - m) : 0.0f;
    float s = e;
    #pragma unroll
    for(int off = 32; off; off >>= 1) s += __shfl_xor(s, off, 64);
    if(lane < 40) io[v*40 + lane] = val - m - __logf(s);
}

extern "C" void kernel_launch(void* const* d_in, const int* in_sizes, int n_in,
                              void* d_out, int out_size, void* d_ws, size_t ws_size,
                              hipStream_t stream){
    const float* x   = (const float*)d_in[0];
    const int*   e32 = (const int*)  d_in[1];
    const float* W1  = (const float*)d_in[2];
    const float* b1  = (const float*)d_in[3];
    const float* W2  = (const float*)d_in[4];
    const float* b2  = (const float*)d_in[5];
    const float* W3  = (const float*)d_in[6];
    const float* b3  = (const float*)d_in[7];
    float* out = (float*)d_out;

    char* ws = (char*)d_ws;
    size_t off = 0;
    auto alloc = [&](size_t bytes) -> void* {
        void* p = ws + off;
        off = (off + bytes + 255) & ~(size_t)255;
        return p;
    };
    int*   cnt    = (int*)  alloc((size_t)NN*4);
    int*   rp     = (int*)  alloc((size_t)(NN+1)*4);
    int*   cursor = (int*)  alloc((size_t)NN*4);
    int*   bsums  = (int*)  alloc(512*4);
    int*   flag   = (int*)  alloc(256);
    float* dinv   = (float*)alloc((size_t)NN*4);
    int*   csr_s  = (int*)  alloc((size_t)NE*4);
    float* csr_w  = (float*)alloc((size_t)NE*4);
    float* bufA   = (float*)alloc((size_t)NN*64*4);
    float* bufB   = (float*)alloc((size_t)NN*64*4);

    hipMemsetAsync(cnt, 0, (size_t)NN*4, stream);
    detect_k<<<1, 64, 0, stream>>>(e32, flag);
    count_k<<<(NE+255)/256, 256, 0, stream>>>(e32, flag, cnt);
    dinv_k<<<(NN+255)/256, 256, 0, stream>>>(cnt, dinv);
    const int NB = (NN + 255)/256;   // 391
    scan_a<<<NB, 256, 0, stream>>>(cnt, rp, bsums);
    scan_b<<<1, 512, 0, stream>>>(bsums, NB);
    scan_c<<<NB, 256, 0, stream>>>(rp, bsums, cursor);
    fill_k<<<(NE+255)/256, 256, 0, stream>>>(e32, flag, cursor, dinv, csr_s, csr_w);

    const int GEMM_GRID = (NN + 63)/64;       // 1563
    const int AGG_GRID  = (NN*64 + 255)/256;  // 25000

    gemm_k<128,64,false><<<GEMM_GRID, 256, 0, stream>>>(x,    W1, bufA, NN);
    agg_k<64><<<AGG_GRID, 256, 0, stream>>>(bufA, rp, csr_s, csr_w, dinv, b1, bufB);
    gemm_k<64,64,true><<<GEMM_GRID, 256, 0, stream>>>(bufB, W2, bufA, NN);
    agg_k<64><<<AGG_GRID, 256, 0, stream>>>(bufA, rp, csr_s, csr_w, dinv, b2, bufB);
    gemm_k<64,40,true><<<GEMM_GRID, 256, 0, stream>>>(bufB, W3, bufA, NN);
    agg_k<40><<<AGG_GRID, 256, 0, stream>>>(bufA, rp, csr_s, csr_w, dinv, b3, out);
    lsm_k<<<AGG_GRID, 256, 0, stream>>>(out);
}

// Round 2
// 422.474 us; speedup vs baseline: 1.4861x; 1.4861x over previous
//
#include <hip/hip_runtime.h>

#define NN 100000
#define NE 1250000

// ---------------- edge dtype detection (int32 vs int64) ----------------
__global__ __launch_bounds__(64) void detect_k(const int* __restrict__ e32, int* __restrict__ flag){
    int lane = threadIdx.x;
    int v = e32[2*lane + 1];                 // high word if int64, else a src value
    unsigned long long b = __ballot(v != 0);
    if(lane == 0) flag[0] = (b == 0ULL) ? 1 : 0;   // 1 => int64 layout
}

// ---------------- degree count ----------------
__global__ __launch_bounds__(256) void count_k(const int* __restrict__ e32, const int* __restrict__ flag,
                                               int* __restrict__ cnt){
    int i = blockIdx.x*256 + threadIdx.x;
    if(i >= NE) return;
    int f = flag[0];
    int d = e32[f ? 2*(NE + i) : (NE + i)];
    atomicAdd(&cnt[d], 1);
}

__global__ __launch_bounds__(256) void dinv_k(const int* __restrict__ cnt, float* __restrict__ dinv){
    int i = blockIdx.x*256 + threadIdx.x;
    if(i < NN) dinv[i] = rsqrtf((float)(cnt[i] + 1));   // +1 = self loop
}

// ---------------- exclusive scan (3 kernels) ----------------
__global__ __launch_bounds__(256) void scan_a(const int* __restrict__ cnt, int* __restrict__ rp,
                                              int* __restrict__ bsums){
    __shared__ int s[256];
    int i = blockIdx.x*256 + threadIdx.x;
    int v = (i < NN) ? cnt[i] : 0;
    s[threadIdx.x] = v; __syncthreads();
    for(int off = 1; off < 256; off <<= 1){
        int t = (threadIdx.x >= off) ? s[threadIdx.x - off] : 0;
        __syncthreads();
        s[threadIdx.x] += t;
        __syncthreads();
    }
    if(i < NN) rp[i] = s[threadIdx.x] - v;          // exclusive
    if(threadIdx.x == 255) bsums[blockIdx.x] = s[255];
}

__global__ __launch_bounds__(512) void scan_b(int* __restrict__ bsums, int nb){
    __shared__ int s[512];
    int t = threadIdx.x;
    int v = (t < nb) ? bsums[t] : 0;
    s[t] = v; __syncthreads();
    for(int off = 1; off < 512; off <<= 1){
        int u = (t >= off) ? s[t - off] : 0;
        __syncthreads();
        s[t] += u;
        __syncthreads();
    }
    if(t < nb) bsums[t] = s[t] - v;                  // exclusive block offsets
}

__global__ __launch_bounds__(256) void scan_c(int* __restrict__ rp, const int* __restrict__ bsums,
                                              int* __restrict__ cursor){
    int i = blockIdx.x*256 + threadIdx.x;
    if(i < NN){
        int v = rp[i] + bsums[blockIdx.x];
        rp[i] = v;
        cursor[i] = v;
    }
    if(i == 0) rp[NN] = NE;
}

// ---------------- CSR fill ----------------
__global__ __launch_bounds__(256) void fill_k(const int* __restrict__ e32, const int* __restrict__ flag,
                                              int* __restrict__ cursor, const float* __restrict__ dinv,
                                              int* __restrict__ csr_src, float* __restrict__ csr_w){
    int i = blockIdx.x*256 + threadIdx.x;
    if(i >= NE) return;
    int f = flag[0];
    int s = e32[f ? 2*i        : i];
    int d = e32[f ? 2*(NE + i) : (NE + i)];
    int pos = atomicAdd(&cursor[d], 1);
    csr_src[pos] = s;
    csr_w[pos]   = dinv[s] * dinv[d];
}

// ---------------- dense GEMM: [M,K] @ [K,NC] -> [M,NC], optional relu on input ----------------
template<int K, int NC, bool RELU>
__global__ __launch_bounds__(256) void gemm_k(const float* __restrict__ A, const float* __restrict__ W,
                                              float* __restrict__ out, int M){
    constexpr int CH = K/4;          // float4 chunks per row
    constexpr int CMASK = CH - 1;
    __shared__ float Xs[64*K];
    __shared__ float Ws[K*NC];
    const int tid  = threadIdx.x;
    const int base = blockIdx.x * 64;

    for(int idx = tid; idx < K*NC; idx += 256) Ws[idx] = W[idx];

    for(int idx = tid; idx < 64*K; idx += 256){
        int r = idx / K;
        int k = idx % K;
        int row = base + r; if(row >= M) row = M - 1;
        float v = A[(size_t)row*K + k];
        if(RELU) v = fmaxf(v, 0.0f);
        int sw = ((k >> 2) + r) & CMASK;           // rotate-swizzle chunks to avoid bank conflicts
        Xs[r*K + (sw << 2) + (k & 3)] = v;
    }
    __syncthreads();

    const int tx = tid & 15, ty = tid >> 4;
    const int c0 = tx * 4;
    float acc[4][4] = {};
    if(c0 < NC){
        for(int k4 = 0; k4 < CH; ++k4){
            float4 xs[4];
            #pragma unroll
            for(int i = 0; i < 4; ++i){
                int r = ty*4 + i;
                int sw = (k4 + r) & CMASK;
                xs[i] = *(const float4*)&Xs[r*K + (sw << 2)];
            }
            float4 wsv[4];
            #pragma unroll
            for(int kk = 0; kk < 4; ++kk) wsv[kk] = *(const float4*)&Ws[(k4*4 + kk)*NC + c0];
            #pragma unroll
            for(int kk = 0; kk < 4; ++kk){
                const float* wp = (const float*)&wsv[kk];
                #pragma unroll
                for(int i = 0; i < 4; ++i){
                    float xv = ((const float*)&xs[i])[kk];
                    #pragma unroll
                    for(int j = 0; j < 4; ++j) acc[i][j] += xv * wp[j];
                }
            }
        }
    }
    #pragma unroll
    for(int i = 0; i < 4; ++i){
        int row = base + ty*4 + i;
        if(row < M && c0 < NC){
            float4 o; o.x = acc[i][0]; o.y = acc[i][1]; o.z = acc[i][2]; o.w = acc[i][3];
            *(float4*)&out[(size_t)row*NC + c0] = o;
        }
    }
}

// ---------------- CSR aggregation, unroll-4 for memory-level parallelism ----------------
// G[v] = b + sum_{s in N(v)} H[s]*w + H[v]*dinv[v]^2 ; optional fused log_softmax.
template<int F, bool LSM>
__global__ __launch_bounds__(256) void agg_k(const float* __restrict__ H, const int* __restrict__ rp,
                                             const int* __restrict__ csr_src, const float* __restrict__ csr_w,
                                             const float* __restrict__ dinv, const float* __restrict__ bias,
                                             float* __restrict__ G){
    const int lane = threadIdx.x & 63;
    const int v = (blockIdx.x*256 + threadIdx.x) >> 6;
    if(v >= NN) return;
    const int c = (F == 64) ? lane : (lane < F ? lane : 0);   // clamp keeps loop non-divergent
    const float d = dinv[v];
    const int beg = rp[v], end = rp[v + 1];
    float acc = bias[c] + H[(size_t)v*F + c] * d * d;
    int j = beg;
    #pragma unroll 1
    for(; j + 4 <= end; j += 4){
        int   s0 = csr_src[j+0], s1 = csr_src[j+1], s2 = csr_src[j+2], s3 = csr_src[j+3];
        float w0 = csr_w[j+0],  w1 = csr_w[j+1],  w2 = csr_w[j+2],  w3 = csr_w[j+3];
        float h0 = H[(size_t)s0*F + c];
        float h1 = H[(size_t)s1*F + c];
        float h2 = H[(size_t)s2*F + c];
        float h3 = H[(size_t)s3*F + c];
        acc = fmaf(h0, w0, acc);
        acc = fmaf(h1, w1, acc);
        acc = fmaf(h2, w2, acc);
        acc = fmaf(h3, w3, acc);
    }
    for(; j < end; ++j){
        int s = csr_src[j];
        acc = fmaf(H[(size_t)s*F + c], csr_w[j], acc);
    }
    if(!LSM){
        if(lane < F) G[(size_t)v*F + lane] = acc;
    } else {
        float val = (lane < F) ? acc : -3.402823466e38f;
        float m = val;
        #pragma unroll
        for(int off = 32; off; off >>= 1) m = fmaxf(m, __shfl_xor(m, off, 64));
        float e = (lane < F) ? __expf(val - m) : 0.0f;
        float s = e;
        #pragma unroll
        for(int off = 32; off; off >>= 1) s += __shfl_xor(s, off, 64);
        if(lane < F) G[(size_t)v*F + lane] = val - m - __logf(s);
    }
}

extern "C" void kernel_launch(void* const* d_in, const int* in_sizes, int n_in,
                              void* d_out, int out_size, void* d_ws, size_t ws_size,
                              hipStream_t stream){
    const float* x   = (const float*)d_in[0];
    const int*   e32 = (const int*)  d_in[1];
    const float* W1  = (const float*)d_in[2];
    const float* b1  = (const float*)d_in[3];
    const float* W2  = (const float*)d_in[4];
    const float* b2  = (const float*)d_in[5];
    const float* W3  = (const float*)d_in[6];
    const float* b3  = (const float*)d_in[7];
    float* out = (float*)d_out;

    char* ws = (char*)d_ws;
    size_t off = 0;
    auto alloc = [&](size_t bytes) -> void* {
        void* p = ws + off;
        off = (off + bytes + 255) & ~(size_t)255;
        return p;
    };
    int*   cnt    = (int*)  alloc((size_t)NN*4);
    int*   rp     = (int*)  alloc((size_t)(NN+1)*4);
    int*   cursor = (int*)  alloc((size_t)NN*4);
    int*   bsums  = (int*)  alloc(512*4);
    int*   flag   = (int*)  alloc(256);
    float* dinv   = (float*)alloc((size_t)NN*4);
    int*   csr_s  = (int*)  alloc((size_t)NE*4);
    float* csr_w  = (float*)alloc((size_t)NE*4);
    float* bufA   = (float*)alloc((size_t)NN*64*4);
    float* bufB   = (float*)alloc((size_t)NN*64*4);

    hipMemsetAsync(cnt, 0, (size_t)NN*4, stream);
    detect_k<<<1, 64, 0, stream>>>(e32, flag);
    count_k<<<(NE+255)/256, 256, 0, stream>>>(e32, flag, cnt);
    dinv_k<<<(NN+255)/256, 256, 0, stream>>>(cnt, dinv);
    const int NB = (NN + 255)/256;   // 391
    scan_a<<<NB, 256, 0, stream>>>(cnt, rp, bsums);
    scan_b<<<1, 512, 0, stream>>>(bsums, NB);
    scan_c<<<NB, 256, 0, stream>>>(rp, bsums, cursor);
    fill_k<<<(NE+255)/256, 256, 0, stream>>>(e32, flag, cursor, dinv, csr_s, csr_w);

    const int GEMM_GRID = (NN + 63)/64;       // 1563
    const int AGG_GRID  = (NN*64 + 255)/256;  // 25000

    gemm_k<128,64,false><<<GEMM_GRID, 256, 0, stream>>>(x,    W1, bufA, NN);
    agg_k<64,false><<<AGG_GRID, 256, 0, stream>>>(bufA, rp, csr_s, csr_w, dinv, b1, bufB);
    gemm_k<64,64,true><<<GEMM_GRID, 256, 0, stream>>>(bufB, W2, bufA, NN);
    agg_k<64,false><<<AGG_GRID, 256, 0, stream>>>(bufA, rp, csr_s, csr_w, dinv, b2, bufB);
    gemm_k<64,40,true><<<GEMM_GRID, 256, 0, stream>>>(bufB, W3, bufA, NN);
    agg_k<40,true><<<AGG_GRID, 256, 0, stream>>>(bufA, rp, csr_s, csr_w, dinv, b3, out);
}

// Round 3
// 421.973 us; speedup vs baseline: 1.4878x; 1.0012x over previous
//
#include <hip/hip_runtime.h>

#define NN 100000
#define NE 1250000

// ---------------- edge dtype detection (int32 vs int64) ----------------
__global__ __launch_bounds__(64) void detect_k(const int* __restrict__ e32, int* __restrict__ flag){
    int lane = threadIdx.x;
    int v = e32[2*lane + 1];                 // high word if int64, else a src value
    unsigned long long b = __ballot(v != 0);
    if(lane == 0) flag[0] = (b == 0ULL) ? 1 : 0;   // 1 => int64 layout
}

// ---------------- degree count, 4 edges/thread for atomic pipelining ----------------
__global__ __launch_bounds__(256) void count_k(const int* __restrict__ e32, const int* __restrict__ flag,
                                               int* __restrict__ cnt){
    int base = (blockIdx.x*256 + threadIdx.x)*4;
    if(base >= NE) return;                       // NE % 4 == 0
    int f = flag[0];
    int d0 = e32[f ? 2*(NE + base+0) : (NE + base+0)];
    int d1 = e32[f ? 2*(NE + base+1) : (NE + base+1)];
    int d2 = e32[f ? 2*(NE + base+2) : (NE + base+2)];
    int d3 = e32[f ? 2*(NE + base+3) : (NE + base+3)];
    atomicAdd(&cnt[d0], 1);
    atomicAdd(&cnt[d1], 1);
    atomicAdd(&cnt[d2], 1);
    atomicAdd(&cnt[d3], 1);
}

__global__ __launch_bounds__(256) void dinv_k(const int* __restrict__ cnt, float* __restrict__ dinv){
    int i = blockIdx.x*256 + threadIdx.x;
    if(i < NN) dinv[i] = rsqrtf((float)(cnt[i] + 1));   // +1 = self loop
}

// ---------------- exclusive scan (3 kernels) ----------------
__global__ __launch_bounds__(256) void scan_a(const int* __restrict__ cnt, int* __restrict__ rp,
                                              int* __restrict__ bsums){
    __shared__ int s[256];
    int i = blockIdx.x*256 + threadIdx.x;
    int v = (i < NN) ? cnt[i] : 0;
    s[threadIdx.x] = v; __syncthreads();
    for(int off = 1; off < 256; off <<= 1){
        int t = (threadIdx.x >= off) ? s[threadIdx.x - off] : 0;
        __syncthreads();
        s[threadIdx.x] += t;
        __syncthreads();
    }
    if(i < NN) rp[i] = s[threadIdx.x] - v;          // exclusive
    if(threadIdx.x == 255) bsums[blockIdx.x] = s[255];
}

__global__ __launch_bounds__(512) void scan_b(int* __restrict__ bsums, int nb){
    __shared__ int s[512];
    int t = threadIdx.x;
    int v = (t < nb) ? bsums[t] : 0;
    s[t] = v; __syncthreads();
    for(int off = 1; off < 512; off <<= 1){
        int u = (t >= off) ? s[t - off] : 0;
        __syncthreads();
        s[t] += u;
        __syncthreads();
    }
    if(t < nb) bsums[t] = s[t] - v;                  // exclusive block offsets
}

__global__ __launch_bounds__(256) void scan_c(int* __restrict__ rp, const int* __restrict__ bsums,
                                              int* __restrict__ cursor){
    int i = blockIdx.x*256 + threadIdx.x;
    if(i < NN){
        int v = rp[i] + bsums[blockIdx.x];
        rp[i] = v;
        cursor[i] = v;
    }
    if(i == 0) rp[NN] = NE;
}

// ---------------- CSR fill: src only (weights factored out), 4 edges/thread ----------------
__global__ __launch_bounds__(256) void fill_k(const int* __restrict__ e32, const int* __restrict__ flag,
                                              int* __restrict__ cursor, int* __restrict__ csr_src){
    int base = (blockIdx.x*256 + threadIdx.x)*4;
    if(base >= NE) return;                       // NE % 4 == 0
    int f = flag[0];
    int s0 = e32[f ? 2*(base+0) : (base+0)];
    int s1 = e32[f ? 2*(base+1) : (base+1)];
    int s2 = e32[f ? 2*(base+2) : (base+2)];
    int s3 = e32[f ? 2*(base+3) : (base+3)];
    int d0 = e32[f ? 2*(NE + base+0) : (NE + base+0)];
    int d1 = e32[f ? 2*(NE + base+1) : (NE + base+1)];
    int d2 = e32[f ? 2*(NE + base+2) : (NE + base+2)];
    int d3 = e32[f ? 2*(NE + base+3) : (NE + base+3)];
    int p0 = atomicAdd(&cursor[d0], 1);
    int p1 = atomicAdd(&cursor[d1], 1);
    int p2 = atomicAdd(&cursor[d2], 1);
    int p3 = atomicAdd(&cursor[d3], 1);
    csr_src[p0] = s0;
    csr_src[p1] = s1;
    csr_src[p2] = s2;
    csr_src[p3] = s3;
}

// ---------------- dense GEMM: out[row] = (A@W)[row] * dinv[row]; optional relu on input ----------------
template<int K, int NC, bool RELU>
__global__ __launch_bounds__(256) void gemm_k(const float* __restrict__ A, const float* __restrict__ W,
                                              const float* __restrict__ dinv,
                                              float* __restrict__ out, int M){
    constexpr int CH = K/4;          // float4 chunks per row
    constexpr int CMASK = CH - 1;
    __shared__ float Xs[64*K];
    __shared__ float Ws[K*NC];
    const int tid  = threadIdx.x;
    const int base = blockIdx.x * 64;

    for(int idx = tid; idx < K*NC; idx += 256) Ws[idx] = W[idx];

    for(int idx = tid; idx < 64*K; idx += 256){
        int r = idx / K;
        int k = idx % K;
        int row = base + r; if(row >= M) row = M - 1;
        float v = A[(size_t)row*K + k];
        if(RELU) v = fmaxf(v, 0.0f);
        int sw = ((k >> 2) + r) & CMASK;           // rotate-swizzle chunks to avoid bank conflicts
        Xs[r*K + (sw << 2) + (k & 3)] = v;
    }
    __syncthreads();

    const int tx = tid & 15, ty = tid >> 4;
    const int c0 = tx * 4;
    float acc[4][4] = {};
    if(c0 < NC){
        for(int k4 = 0; k4 < CH; ++k4){
            float4 xs[4];
            #pragma unroll
            for(int i = 0; i < 4; ++i){
                int r = ty*4 + i;
                int sw = (k4 + r) & CMASK;
                xs[i] = *(const float4*)&Xs[r*K + (sw << 2)];
            }
            float4 wsv[4];
            #pragma unroll
            for(int kk = 0; kk < 4; ++kk) wsv[kk] = *(const float4*)&Ws[(k4*4 + kk)*NC + c0];
            #pragma unroll
            for(int kk = 0; kk < 4; ++kk){
                const float* wp = (const float*)&wsv[kk];
                #pragma unroll
                for(int i = 0; i < 4; ++i){
                    float xv = ((const float*)&xs[i])[kk];
                    #pragma unroll
                    for(int j = 0; j < 4; ++j) acc[i][j] += xv * wp[j];
                }
            }
        }
    }
    #pragma unroll
    for(int i = 0; i < 4; ++i){
        int row = base + ty*4 + i;
        if(row < M && c0 < NC){
            float dv = dinv[row];
            float4 o; o.x = acc[i][0]*dv; o.y = acc[i][1]*dv; o.z = acc[i][2]*dv; o.w = acc[i][3]*dv;
            *(float4*)&out[(size_t)row*NC + c0] = o;
        }
    }
}

// ---------------- CSR aggregation: G[v] = b + dinv[v] * (sum_{s in N(v)} P[s] + P[v]) ----------------
// P is pre-scaled by dinv on the gemm side. Optional fused log_softmax.
template<int F, bool LSM>
__global__ __launch_bounds__(256) void agg_k(const float* __restrict__ P, const int* __restrict__ rp,
                                             const int* __restrict__ csr_src,
                                             const float* __restrict__ dinv, const float* __restrict__ bias,
                                             float* __restrict__ G){
    const int lane = threadIdx.x & 63;
    const int v = (blockIdx.x*256 + threadIdx.x) >> 6;
    if(v >= NN) return;
    const int c = (F == 64) ? lane : (lane < F ? lane : 0);   // clamp keeps loop non-divergent
    const int beg = rp[v], end = rp[v + 1];
    float acc = P[(size_t)v*F + c];                 // self-loop term
    int j = beg;
    #pragma unroll 1
    for(; j + 8 <= end; j += 8){
        int s[8]; float h[8];
        #pragma unroll
        for(int u = 0; u < 8; ++u) s[u] = csr_src[j+u];
        #pragma unroll
        for(int u = 0; u < 8; ++u) h[u] = P[(size_t)s[u]*F + c];
        #pragma unroll
        for(int u = 0; u < 8; ++u) acc += h[u];
    }
    if(j + 4 <= end){
        int s[4]; float h[4];
        #pragma unroll
        for(int u = 0; u < 4; ++u) s[u] = csr_src[j+u];
        #pragma unroll
        for(int u = 0; u < 4; ++u) h[u] = P[(size_t)s[u]*F + c];
        #pragma unroll
        for(int u = 0; u < 4; ++u) acc += h[u];
        j += 4;
    }
    for(; j < end; ++j){
        int s = csr_src[j];
        acc += P[(size_t)s*F + c];
    }
    acc = fmaf(acc, dinv[v], bias[c]);
    if(!LSM){
        if(lane < F) G[(size_t)v*F + lane] = acc;
    } else {
        float val = (lane < F) ? acc : -3.402823466e38f;
        float m = val;
        #pragma unroll
        for(int off = 32; off; off >>= 1) m = fmaxf(m, __shfl_xor(m, off, 64));
        float e = (lane < F) ? __expf(val - m) : 0.0f;
        float s = e;
        #pragma unroll
        for(int off = 32; off; off >>= 1) s += __shfl_xor(s, off, 64);
        if(lane < F) G[(size_t)v*F + lane] = val - m - __logf(s);
    }
}

extern "C" void kernel_launch(void* const* d_in, const int* in_sizes, int n_in,
                              void* d_out, int out_size, void* d_ws, size_t ws_size,
                              hipStream_t stream){
    const float* x   = (const float*)d_in[0];
    const int*   e32 = (const int*)  d_in[1];
    const float* W1  = (const float*)d_in[2];
    const float* b1  = (const float*)d_in[3];
    const float* W2  = (const float*)d_in[4];
    const float* b2  = (const float*)d_in[5];
    const float* W3  = (const float*)d_in[6];
    const float* b3  = (const float*)d_in[7];
    float* out = (float*)d_out;

    char* ws = (char*)d_ws;
    size_t off = 0;
    auto alloc = [&](size_t bytes) -> void* {
        void* p = ws + off;
        off = (off + bytes + 255) & ~(size_t)255;
        return p;
    };
    int*   cnt    = (int*)  alloc((size_t)NN*4);
    int*   rp     = (int*)  alloc((size_t)(NN+1)*4);
    int*   cursor = (int*)  alloc((size_t)NN*4);
    int*   bsums  = (int*)  alloc(512*4);
    int*   flag   = (int*)  alloc(256);
    float* dinv   = (float*)alloc((size_t)NN*4);
    int*   csr_s  = (int*)  alloc((size_t)NE*4);
    float* bufA   = (float*)alloc((size_t)NN*64*4);
    float* bufB   = (float*)alloc((size_t)NN*64*4);

    hipMemsetAsync(cnt, 0, (size_t)NN*4, stream);
    detect_k<<<1, 64, 0, stream>>>(e32, flag);
    count_k<<<(NE/4 + 255)/256, 256, 0, stream>>>(e32, flag, cnt);
    dinv_k<<<(NN+255)/256, 256, 0, stream>>>(cnt, dinv);
    const int NB = (NN + 255)/256;   // 391
    scan_a<<<NB, 256, 0, stream>>>(cnt, rp, bsums);
    scan_b<<<1, 512, 0, stream>>>(bsums, NB);
    scan_c<<<NB, 256, 0, stream>>>(rp, bsums, cursor);
    fill_k<<<(NE/4 + 255)/256, 256, 0, stream>>>(e32, flag, cursor, csr_s);

    const int GEMM_GRID = (NN + 63)/64;       // 1563
    const int AGG_GRID  = (NN*64 + 255)/256;  // 25000

    gemm_k<128,64,false><<<GEMM_GRID, 256, 0, stream>>>(x,    W1, dinv, bufA, NN);
    agg_k<64,false><<<AGG_GRID, 256, 0, stream>>>(bufA, rp, csr_s, dinv, b1, bufB);
    gemm_k<64,64,true><<<GEMM_GRID, 256, 0, stream>>>(bufB, W2, dinv, bufA, NN);
    agg_k<64,false><<<AGG_GRID, 256, 0, stream>>>(bufA, rp, csr_s, dinv, b2, bufB);
    gemm_k<64,40,true><<<GEMM_GRID, 256, 0, stream>>>(bufB, W3, dinv, bufA, NN);
    agg_k<40,true><<<AGG_GRID, 256, 0, stream>>>(bufA, rp, csr_s, dinv, b3, out);
}

// Round 4
// 345.778 us; speedup vs baseline: 1.8157x; 1.2204x over previous
//
#include <hip/hip_runtime.h>

#define NN 100000
#define NE 1250000
#define NBIN 512
#define RBIN 196          // ceil(NN/NBIN); bin b covers nodes [b*196, b*196+196)
#define PAD 16            // counter padding: 16 ints = 64B line
#define CAP 4096          // LDS edge-staging capacity (int2 = 32KB)

// ---------------- edge dtype detection (int32 vs int64) ----------------
__global__ __launch_bounds__(64) void detect_k(const int* __restrict__ e32, int* __restrict__ flag){
    int lane = threadIdx.x;
    int v = e32[2*lane + 1];                 // high word if int64, else a src value
    unsigned long long b = __ballot(v != 0);
    if(lane == 0) flag[0] = (b == 0ULL) ? 1 : 0;   // 1 => int64 layout
}

__device__ __forceinline__ int eidx(const int* __restrict__ e32, int f, int i){
    return f ? e32[2*(size_t)i] : e32[i];
}

// ---------------- pass A: per-bin edge counts (LDS histogram) ----------------
__global__ __launch_bounds__(256) void binA_k(const int* __restrict__ e32, const int* __restrict__ flag,
                                              int* __restrict__ binCnt){
    __shared__ int h[NBIN];
    for(int t = threadIdx.x; t < NBIN; t += 256) h[t] = 0;
    __syncthreads();
    int f = flag[0];
    int base = blockIdx.x * 2048;
    #pragma unroll
    for(int k = 0; k < 8; ++k){
        int i = base + k*256 + threadIdx.x;
        if(i < NE){
            int d = eidx(e32, f, NE + i);
            atomicAdd(&h[d / RBIN], 1);
        }
    }
    __syncthreads();
    for(int t = threadIdx.x; t < NBIN; t += 256){
        int v = h[t];
        if(v) atomicAdd(&binCnt[t*PAD], v);
    }
}

// ---------------- pass B: scan bin counts -> bin offsets (= coarse CSR offsets) ----------------
__global__ __launch_bounds__(512) void binB_k(const int* __restrict__ binCnt, int* __restrict__ binOff,
                                              int* __restrict__ binCur, int* __restrict__ rp){
    __shared__ int s[NBIN];
    int t = threadIdx.x;
    int v = binCnt[t*PAD];
    s[t] = v; __syncthreads();
    for(int off = 1; off < NBIN; off <<= 1){
        int u = (t >= off) ? s[t - off] : 0;
        __syncthreads();
        s[t] += u;
        __syncthreads();
    }
    int e = s[t] - v;          // exclusive
    binOff[t] = e;
    binCur[t*PAD] = e;
    if(t == NBIN-1){ binOff[NBIN] = NE; rp[NN] = NE; }
}

// ---------------- pass C: scatter (src,dst) pairs into dst-bins ----------------
__global__ __launch_bounds__(256) void binC_k(const int* __restrict__ e32, const int* __restrict__ flag,
                                              int* __restrict__ binCur, int2* __restrict__ bins){
    int i0 = (blockIdx.x*256 + threadIdx.x)*2;
    if(i0 >= NE) return;                         // NE % 2 == 0
    int f = flag[0];
    int s0 = eidx(e32, f, i0),      s1 = eidx(e32, f, i0+1);
    int d0 = eidx(e32, f, NE + i0), d1 = eidx(e32, f, NE + i0+1);
    int p0 = atomicAdd(&binCur[(d0/RBIN)*PAD], 1);
    int p1 = atomicAdd(&binCur[(d1/RBIN)*PAD], 1);
    bins[p0] = make_int2(s0, d0);
    bins[p1] = make_int2(s1, d1);
}

// ---------------- pass D: per-bin CSR build (rp, dinv, csr_src) ----------------
__global__ __launch_bounds__(256) void binD_k(const int2* __restrict__ bins, const int* __restrict__ binOff,
                                              int* __restrict__ rp, float* __restrict__ dinv,
                                              int* __restrict__ csr_src){
    __shared__ int2 ES[CAP];
    __shared__ int hist[256];
    __shared__ int sc[256];
    __shared__ int cur[256];
    const int b = blockIdx.x;
    const int nbase = b * RBIN;
    if(nbase >= NN) return;                      // empty trailing bin
    const int nend = min(nbase + RBIN, NN);
    const int nr = nend - nbase;
    const int off0 = binOff[b];
    const int cnt  = binOff[b+1] - off0;
    const int t = threadIdx.x;
    hist[t] = 0; cur[t] = 0;
    __syncthreads();

    const bool single = (cnt <= CAP);
    // histogram phase
    for(int c0 = 0; c0 < cnt; c0 += CAP){
        int n = min(CAP, cnt - c0);
        for(int i = t; i < n; i += 256) ES[i] = bins[off0 + c0 + i];
        __syncthreads();
        for(int i = t; i < n; i += 256) atomicAdd(&hist[ES[i].y - nbase], 1);
        __syncthreads();
    }
    // exclusive scan of hist into sc
    int v = hist[t];
    sc[t] = v; __syncthreads();
    for(int off = 1; off < 256; off <<= 1){
        int u = (t >= off) ? sc[t - off] : 0;
        __syncthreads();
        sc[t] += u;
        __syncthreads();
    }
    int excl = sc[t] - v;
    sc[t] = excl;
    if(t < nr){
        rp[nbase + t]   = off0 + excl;
        dinv[nbase + t] = rsqrtf((float)(v + 1));   // +1 = self loop
    }
    __syncthreads();
    // scatter phase (ES still valid if single chunk)
    for(int c0 = 0; c0 < cnt; c0 += CAP){
        int n = min(CAP, cnt - c0);
        if(!single){
            for(int i = t; i < n; i += 256) ES[i] = bins[off0 + c0 + i];
            __syncthreads();
        }
        for(int i = t; i < n; i += 256){
            int dl = ES[i].y - nbase;
            int p = atomicAdd(&cur[dl], 1);
            csr_src[off0 + sc[dl] + p] = ES[i].x;
        }
        if(!single) __syncthreads();
    }
}

// ---------------- dense GEMM: out[row] = (A@W)[row] * dinv[row]; optional relu on input ----------------
template<int K, int NC, bool RELU>
__global__ __launch_bounds__(256) void gemm_k(const float* __restrict__ A, const float* __restrict__ W,
                                              const float* __restrict__ dinv,
                                              float* __restrict__ out, int M){
    constexpr int CH = K/4;          // float4 chunks per row
    constexpr int CMASK = CH - 1;
    __shared__ float Xs[64*K];
    __shared__ float Ws[K*NC];
    const int tid  = threadIdx.x;
    const int base = blockIdx.x * 64;

    for(int idx = tid; idx < K*NC; idx += 256) Ws[idx] = W[idx];

    for(int idx = tid; idx < 64*K; idx += 256){
        int r = idx / K;
        int k = idx % K;
        int row = base + r; if(row >= M) row = M - 1;
        float v = A[(size_t)row*K + k];
        if(RELU) v = fmaxf(v, 0.0f);
        int sw = ((k >> 2) + r) & CMASK;           // rotate-swizzle chunks to avoid bank conflicts
        Xs[r*K + (sw << 2) + (k & 3)] = v;
    }
    __syncthreads();

    const int tx = tid & 15, ty = tid >> 4;
    const int c0 = tx * 4;
    float acc[4][4] = {};
    if(c0 < NC){
        for(int k4 = 0; k4 < CH; ++k4){
            float4 xs[4];
            #pragma unroll
            for(int i = 0; i < 4; ++i){
                int r = ty*4 + i;
                int sw = (k4 + r) & CMASK;
                xs[i] = *(const float4*)&Xs[r*K + (sw << 2)];
            }
            float4 wsv[4];
            #pragma unroll
            for(int kk = 0; kk < 4; ++kk) wsv[kk] = *(const float4*)&Ws[(k4*4 + kk)*NC + c0];
            #pragma unroll
            for(int kk = 0; kk < 4; ++kk){
                const float* wp = (const float*)&wsv[kk];
                #pragma unroll
                for(int i = 0; i < 4; ++i){
                    float xv = ((const float*)&xs[i])[kk];
                    #pragma unroll
                    for(int j = 0; j < 4; ++j) acc[i][j] += xv * wp[j];
                }
            }
        }
    }
    #pragma unroll
    for(int i = 0; i < 4; ++i){
        int row = base + ty*4 + i;
        if(row < M && c0 < NC){
            float dv = dinv[row];
            float4 o; o.x = acc[i][0]*dv; o.y = acc[i][1]*dv; o.z = acc[i][2]*dv; o.w = acc[i][3]*dv;
            *(float4*)&out[(size_t)row*NC + c0] = o;
        }
    }
}

// ---------------- CSR aggregation: G[v] = b + dinv[v] * (sum_{s in N(v)} P[s] + P[v]) ----------------
// P is pre-scaled by dinv on the gemm side. Optional fused log_softmax.
template<int F, bool LSM>
__global__ __launch_bounds__(256) void agg_k(const float* __restrict__ P, const int* __restrict__ rp,
                                             const int* __restrict__ csr_src,
                                             const float* __restrict__ dinv, const float* __restrict__ bias,
                                             float* __restrict__ G){
    const int lane = threadIdx.x & 63;
    const int v = (blockIdx.x*256 + threadIdx.x) >> 6;
    if(v >= NN) return;
    const int c = (F == 64) ? lane : (lane < F ? lane : 0);   // clamp keeps loop non-divergent
    const int beg = rp[v], end = rp[v + 1];
    float acc = P[(size_t)v*F + c];                 // self-loop term
    int j = beg;
    #pragma unroll 1
    for(; j + 8 <= end; j += 8){
        int s[8]; float h[8];
        #pragma unroll
        for(int u = 0; u < 8; ++u) s[u] = csr_src[j+u];
        #pragma unroll
        for(int u = 0; u < 8; ++u) h[u] = P[(size_t)s[u]*F + c];
        #pragma unroll
        for(int u = 0; u < 8; ++u) acc += h[u];
    }
    if(j + 4 <= end){
        int s[4]; float h[4];
        #pragma unroll
        for(int u = 0; u < 4; ++u) s[u] = csr_src[j+u];
        #pragma unroll
        for(int u = 0; u < 4; ++u) h[u] = P[(size_t)s[u]*F + c];
        #pragma unroll
        for(int u = 0; u < 4; ++u) acc += h[u];
        j += 4;
    }
    for(; j < end; ++j){
        int s = csr_src[j];
        acc += P[(size_t)s*F + c];
    }
    acc = fmaf(acc, dinv[v], bias[c]);
    if(!LSM){
        if(lane < F) G[(size_t)v*F + lane] = acc;
    } else {
        float val = (lane < F) ? acc : -3.402823466e38f;
        float m = val;
        #pragma unroll
        for(int off = 32; off; off >>= 1) m = fmaxf(m, __shfl_xor(m, off, 64));
        float e = (lane < F) ? __expf(val - m) : 0.0f;
        float s = e;
        #pragma unroll
        for(int off = 32; off; off >>= 1) s += __shfl_xor(s, off, 64);
        if(lane < F) G[(size_t)v*F + lane] = val - m - __logf(s);
    }
}

extern "C" void kernel_launch(void* const* d_in, const int* in_sizes, int n_in,
                              void* d_out, int out_size, void* d_ws, size_t ws_size,
                              hipStream_t stream){
    const float* x   = (const float*)d_in[0];
    const int*   e32 = (const int*)  d_in[1];
    const float* W1  = (const float*)d_in[2];
    const float* b1  = (const float*)d_in[3];
    const float* W2  = (const float*)d_in[4];
    const float* b2  = (const float*)d_in[5];
    const float* W3  = (const float*)d_in[6];
    const float* b3  = (const float*)d_in[7];
    float* out = (float*)d_out;

    char* ws = (char*)d_ws;
    size_t off = 0;
    auto alloc = [&](size_t bytes) -> void* {
        void* p = ws + off;
        off = (off + bytes + 255) & ~(size_t)255;
        return p;
    };
    int*   rp     = (int*)  alloc((size_t)(NN+1)*4);
    int*   binCnt = (int*)  alloc((size_t)NBIN*PAD*4);
    int*   binOff = (int*)  alloc((size_t)(NBIN+1)*4);
    int*   binCur = (int*)  alloc((size_t)NBIN*PAD*4);
    int*   flag   = (int*)  alloc(256);
    float* dinv   = (float*)alloc((size_t)NN*4);
    int*   csr_s  = (int*)  alloc((size_t)NE*4);
    float* bufA   = (float*)alloc((size_t)NN*64*4);
    float* bufB   = (float*)alloc((size_t)NN*64*4);
    int2*  bins   = (int2*) bufA;    // bins dead before gemm1 writes bufA

    hipMemsetAsync(binCnt, 0, (size_t)NBIN*PAD*4, stream);
    detect_k<<<1, 64, 0, stream>>>(e32, flag);
    binA_k<<<(NE + 2047)/2048, 256, 0, stream>>>(e32, flag, binCnt);
    binB_k<<<1, 512, 0, stream>>>(binCnt, binOff, binCur, rp);
    binC_k<<<(NE/2 + 255)/256, 256, 0, stream>>>(e32, flag, binCur, bins);
    binD_k<<<NBIN, 256, 0, stream>>>(bins, binOff, rp, dinv, csr_s);

    const int GEMM_GRID = (NN + 63)/64;       // 1563
    const int AGG_GRID  = (NN*64 + 255)/256;  // 25000

    gemm_k<128,64,false><<<GEMM_GRID, 256, 0, stream>>>(x,    W1, dinv, bufA, NN);
    agg_k<64,false><<<AGG_GRID, 256, 0, stream>>>(bufA, rp, csr_s, dinv, b1, bufB);
    gemm_k<64,64,true><<<GEMM_GRID, 256, 0, stream>>>(bufB, W2, dinv, bufA, NN);
    agg_k<64,false><<<AGG_GRID, 256, 0, stream>>>(bufA, rp, csr_s, dinv, b2, bufB);
    gemm_k<64,40,true><<<GEMM_GRID, 256, 0, stream>>>(bufB, W3, dinv, bufA, NN);
    agg_k<40,true><<<AGG_GRID, 256, 0, stream>>>(bufA, rp, csr_s, dinv, b3, out);
}

// Round 5
// 328.044 us; speedup vs baseline: 1.9138x; 1.0541x over previous
//
#include <hip/hip_runtime.h>
#include <hip/hip_fp16.h>

#define NN 100000
#define NE 1250000
#define NBIN 512
#define RBIN 196          // ceil(NN/NBIN); bin b covers nodes [b*196, b*196+196)
#define PAD 16            // counter padding: 16 ints = 64B line
#define CAP 4096          // LDS edge-staging capacity (int2 = 32KB)

// ---------------- edge dtype detection (int32 vs int64) ----------------
__global__ __launch_bounds__(64) void detect_k(const int* __restrict__ e32, int* __restrict__ flag){
    int lane = threadIdx.x;
    int v = e32[2*lane + 1];                 // high word if int64, else a src value
    unsigned long long b = __ballot(v != 0);
    if(lane == 0) flag[0] = (b == 0ULL) ? 1 : 0;   // 1 => int64 layout
}

__device__ __forceinline__ int eidx(const int* __restrict__ e32, int f, int i){
    return f ? e32[2*(size_t)i] : e32[i];
}

// ---------------- pass A: per-bin edge counts (LDS histogram) ----------------
__global__ __launch_bounds__(256) void binA_k(const int* __restrict__ e32, const int* __restrict__ flag,
                                              int* __restrict__ binCnt){
    __shared__ int h[NBIN];
    for(int t = threadIdx.x; t < NBIN; t += 256) h[t] = 0;
    __syncthreads();
    int f = flag[0];
    int base = blockIdx.x * 2048;
    #pragma unroll
    for(int k = 0; k < 8; ++k){
        int i = base + k*256 + threadIdx.x;
        if(i < NE){
            int d = eidx(e32, f, NE + i);
            atomicAdd(&h[d / RBIN], 1);
        }
    }
    __syncthreads();
    for(int t = threadIdx.x; t < NBIN; t += 256){
        int v = h[t];
        if(v) atomicAdd(&binCnt[t*PAD], v);
    }
}

// ---------------- pass B: scan bin counts -> bin offsets (= coarse CSR offsets) ----------------
__global__ __launch_bounds__(512) void binB_k(const int* __restrict__ binCnt, int* __restrict__ binOff,
                                              int* __restrict__ binCur, int* __restrict__ rp){
    __shared__ int s[NBIN];
    int t = threadIdx.x;
    int v = binCnt[t*PAD];
    s[t] = v; __syncthreads();
    for(int off = 1; off < NBIN; off <<= 1){
        int u = (t >= off) ? s[t - off] : 0;
        __syncthreads();
        s[t] += u;
        __syncthreads();
    }
    int e = s[t] - v;          // exclusive
    binOff[t] = e;
    binCur[t*PAD] = e;
    if(t == NBIN-1){ binOff[NBIN] = NE; rp[NN] = NE; }
}

// ---------------- pass C: scatter (src,dst) pairs into dst-bins ----------------
__global__ __launch_bounds__(256) void binC_k(const int* __restrict__ e32, const int* __restrict__ flag,
                                              int* __restrict__ binCur, int2* __restrict__ bins){
    int i0 = (blockIdx.x*256 + threadIdx.x)*2;
    if(i0 >= NE) return;                         // NE % 2 == 0
    int f = flag[0];
    int s0 = eidx(e32, f, i0),      s1 = eidx(e32, f, i0+1);
    int d0 = eidx(e32, f, NE + i0), d1 = eidx(e32, f, NE + i0+1);
    int p0 = atomicAdd(&binCur[(d0/RBIN)*PAD], 1);
    int p1 = atomicAdd(&binCur[(d1/RBIN)*PAD], 1);
    bins[p0] = make_int2(s0, d0);
    bins[p1] = make_int2(s1, d1);
}

// ---------------- pass D: per-bin CSR build (rp, dinv, csr_src) ----------------
__global__ __launch_bounds__(256) void binD_k(const int2* __restrict__ bins, const int* __restrict__ binOff,
                                              int* __restrict__ rp, float* __restrict__ dinv,
                                              int* __restrict__ csr_src){
    __shared__ int2 ES[CAP];
    __shared__ int hist[256];
    __shared__ int sc[256];
    __shared__ int cur[256];
    const int b = blockIdx.x;
    const int nbase = b * RBIN;
    if(nbase >= NN) return;                      // empty trailing bin
    const int nend = min(nbase + RBIN, NN);
    const int nr = nend - nbase;
    const int off0 = binOff[b];
    const int cnt  = binOff[b+1] - off0;
    const int t = threadIdx.x;
    hist[t] = 0; cur[t] = 0;
    __syncthreads();

    const bool single = (cnt <= CAP);
    // histogram phase
    for(int c0 = 0; c0 < cnt; c0 += CAP){
        int n = min(CAP, cnt - c0);
        for(int i = t; i < n; i += 256) ES[i] = bins[off0 + c0 + i];
        __syncthreads();
        for(int i = t; i < n; i += 256) atomicAdd(&hist[ES[i].y - nbase], 1);
        __syncthreads();
    }
    // exclusive scan of hist into sc
    int v = hist[t];
    sc[t] = v; __syncthreads();
    for(int off = 1; off < 256; off <<= 1){
        int u = (t >= off) ? sc[t - off] : 0;
        __syncthreads();
        sc[t] += u;
        __syncthreads();
    }
    int excl = sc[t] - v;
    sc[t] = excl;
    if(t < nr){
        rp[nbase + t]   = off0 + excl;
        dinv[nbase + t] = rsqrtf((float)(v + 1));   // +1 = self loop
    }
    __syncthreads();
    // scatter phase (ES still valid if single chunk)
    for(int c0 = 0; c0 < cnt; c0 += CAP){
        int n = min(CAP, cnt - c0);
        if(!single){
            for(int i = t; i < n; i += 256) ES[i] = bins[off0 + c0 + i];
            __syncthreads();
        }
        for(int i = t; i < n; i += 256){
            int dl = ES[i].y - nbase;
            int p = atomicAdd(&cur[dl], 1);
            csr_src[off0 + sc[dl] + p] = ES[i].x;
        }
        if(!single) __syncthreads();
    }
}

// ---------------- dense GEMM: out[row] = fp16( (A@W)[row] * dinv[row] ); optional relu on input ----------------
template<int K, int NC, bool RELU>
__global__ __launch_bounds__(256) void gemm_k(const float* __restrict__ A, const float* __restrict__ W,
                                              const float* __restrict__ dinv,
                                              __half* __restrict__ out, int M){
    constexpr int CH = K/4;          // float4 chunks per row
    constexpr int CMASK = CH - 1;
    __shared__ float Xs[64*K];
    __shared__ float Ws[K*NC];
    const int tid  = threadIdx.x;
    const int base = blockIdx.x * 64;

    for(int idx = tid; idx < K*NC; idx += 256) Ws[idx] = W[idx];

    for(int idx = tid; idx < 64*K; idx += 256){
        int r = idx / K;
        int k = idx % K;
        int row = base + r; if(row >= M) row = M - 1;
        float v = A[(size_t)row*K + k];
        if(RELU) v = fmaxf(v, 0.0f);
        int sw = ((k >> 2) + r) & CMASK;           // rotate-swizzle chunks to avoid bank conflicts
        Xs[r*K + (sw << 2) + (k & 3)] = v;
    }
    __syncthreads();

    const int tx = tid & 15, ty = tid >> 4;
    const int c0 = tx * 4;
    float acc[4][4] = {};
    if(c0 < NC){
        for(int k4 = 0; k4 < CH; ++k4){
            float4 xs[4];
            #pragma unroll
            for(int i = 0; i < 4; ++i){
                int r = ty*4 + i;
                int sw = (k4 + r) & CMASK;
                xs[i] = *(const float4*)&Xs[r*K + (sw << 2)];
            }
            float4 wsv[4];
            #pragma unroll
            for(int kk = 0; kk < 4; ++kk) wsv[kk] = *(const float4*)&Ws[(k4*4 + kk)*NC + c0];
            #pragma unroll
            for(int kk = 0; kk < 4; ++kk){
                const float* wp = (const float*)&wsv[kk];
                #pragma unroll
                for(int i = 0; i < 4; ++i){
                    float xv = ((const float*)&xs[i])[kk];
                    #pragma unroll
                    for(int j = 0; j < 4; ++j) acc[i][j] += xv * wp[j];
                }
            }
        }
    }
    #pragma unroll
    for(int i = 0; i < 4; ++i){
        int row = base + ty*4 + i;
        if(row < M && c0 < NC){
            float dv = dinv[row];
            __half2 h01 = __floats2half2_rn(acc[i][0]*dv, acc[i][1]*dv);
            __half2 h23 = __floats2half2_rn(acc[i][2]*dv, acc[i][3]*dv);
            __half2* dst = (__half2*)&out[(size_t)row*NC + c0];
            dst[0] = h01;
            dst[1] = h23;
        }
    }
}

// ---------------- CSR aggregation: G[v] = b + dinv[v] * (sum_{s in N(v)} P[s] + P[v]) ----------------
// P is fp16, pre-scaled by dinv on the gemm side. Accumulate fp32. Optional fused log_softmax.
template<int F, bool LSM>
__global__ __launch_bounds__(256) void agg_k(const __half* __restrict__ P, const int* __restrict__ rp,
                                             const int* __restrict__ csr_src,
                                             const float* __restrict__ dinv, const float* __restrict__ bias,
                                             float* __restrict__ G){
    const int lane = threadIdx.x & 63;
    const int v = (blockIdx.x*256 + threadIdx.x) >> 6;
    if(v >= NN) return;
    const int c = (F == 64) ? lane : (lane < F ? lane : 0);   // clamp keeps loop non-divergent
    const int beg = rp[v], end = rp[v + 1];
    float acc = __half2float(P[(size_t)v*F + c]);   // self-loop term
    int j = beg;
    #pragma unroll 1
    for(; j + 8 <= end; j += 8){
        int s[8]; float h[8];
        #pragma unroll
        for(int u = 0; u < 8; ++u) s[u] = csr_src[j+u];
        #pragma unroll
        for(int u = 0; u < 8; ++u) h[u] = __half2float(P[(size_t)s[u]*F + c]);
        #pragma unroll
        for(int u = 0; u < 8; ++u) acc += h[u];
    }
    if(j + 4 <= end){
        int s[4]; float h[4];
        #pragma unroll
        for(int u = 0; u < 4; ++u) s[u] = csr_src[j+u];
        #pragma unroll
        for(int u = 0; u < 4; ++u) h[u] = __half2float(P[(size_t)s[u]*F + c]);
        #pragma unroll
        for(int u = 0; u < 4; ++u) acc += h[u];
        j += 4;
    }
    for(; j < end; ++j){
        int s = csr_src[j];
        acc += __half2float(P[(size_t)s*F + c]);
    }
    acc = fmaf(acc, dinv[v], bias[c]);
    if(!LSM){
        if(lane < F) G[(size_t)v*F + lane] = acc;
    } else {
        float val = (lane < F) ? acc : -3.402823466e38f;
        float m = val;
        #pragma unroll
        for(int off = 32; off; off >>= 1) m = fmaxf(m, __shfl_xor(m, off, 64));
        float e = (lane < F) ? __expf(val - m) : 0.0f;
        float s = e;
        #pragma unroll
        for(int off = 32; off; off >>= 1) s += __shfl_xor(s, off, 64);
        if(lane < F) G[(size_t)v*F + lane] = val - m - __logf(s);
    }
}

extern "C" void kernel_launch(void* const* d_in, const int* in_sizes, int n_in,
                              void* d_out, int out_size, void* d_ws, size_t ws_size,
                              hipStream_t stream){
    const float* x   = (const float*)d_in[0];
    const int*   e32 = (const int*)  d_in[1];
    const float* W1  = (const float*)d_in[2];
    const float* b1  = (const float*)d_in[3];
    const float* W2  = (const float*)d_in[4];
    const float* b2  = (const float*)d_in[5];
    const float* W3  = (const float*)d_in[6];
    const float* b3  = (const float*)d_in[7];
    float* out = (float*)d_out;

    char* ws = (char*)d_ws;
    size_t off = 0;
    auto alloc = [&](size_t bytes) -> void* {
        void* p = ws + off;
        off = (off + bytes + 255) & ~(size_t)255;
        return p;
    };
    int*    rp     = (int*)   alloc((size_t)(NN+1)*4);
    int*    binCnt = (int*)   alloc((size_t)NBIN*PAD*4);
    int*    binOff = (int*)   alloc((size_t)(NBIN+1)*4);
    int*    binCur = (int*)   alloc((size_t)NBIN*PAD*4);
    int*    flag   = (int*)   alloc(256);
    float*  dinv   = (float*) alloc((size_t)NN*4);
    int*    csr_s  = (int*)   alloc((size_t)NE*4);
    __half* ph     = (__half*)alloc((size_t)NN*64*2);   // fp16 message matrix P
    float*  gA     = (float*) alloc((size_t)NN*64*4);
    float*  gB     = (float*) alloc((size_t)NN*64*4);
    int2*   bins   = (int2*)  gA;    // bins dead before agg1 writes gA

    hipMemsetAsync(binCnt, 0, (size_t)NBIN*PAD*4, stream);
    detect_k<<<1, 64, 0, stream>>>(e32, flag);
    binA_k<<<(NE + 2047)/2048, 256, 0, stream>>>(e32, flag, binCnt);
    binB_k<<<1, 512, 0, stream>>>(binCnt, binOff, binCur, rp);
    binC_k<<<(NE/2 + 255)/256, 256, 0, stream>>>(e32, flag, binCur, bins);
    binD_k<<<NBIN, 256, 0, stream>>>(bins, binOff, rp, dinv, csr_s);

    const int GEMM_GRID = (NN + 63)/64;       // 1563
    const int AGG_GRID  = (NN*64 + 255)/256;  // 25000

    gemm_k<128,64,false><<<GEMM_GRID, 256, 0, stream>>>(x,  W1, dinv, ph, NN);
    agg_k<64,false><<<AGG_GRID, 256, 0, stream>>>(ph, rp, csr_s, dinv, b1, gA);
    gemm_k<64,64,true><<<GEMM_GRID, 256, 0, stream>>>(gA, W2, dinv, ph, NN);
    agg_k<64,false><<<AGG_GRID, 256, 0, stream>>>(ph, rp, csr_s, dinv, b2, gB);
    gemm_k<64,40,true><<<GEMM_GRID, 256, 0, stream>>>(gB, W3, dinv, ph, NN);
    agg_k<40,true><<<AGG_GRID, 256, 0, stream>>>(ph, rp, csr_s, dinv, b3, out);
}

// Round 6
// 280.951 us; speedup vs baseline: 2.2346x; 1.1676x over previous
//
#include <hip/hip_runtime.h>
#include <hip/hip_fp16.h>

#define NN 100000
#define NE 1250000
#define NBIN 512
#define RBIN 196          // ceil(NN/NBIN); bin b covers nodes [b*196, b*196+196)
#define PAD 16            // counter padding: 16 ints = 64B line
#define CAP 4096          // binD LDS edge-staging capacity (int2 = 32KB)
#define EPB 4096          // binC edges per block
#define EPT 16            // EPB/256

// ---------------- edge dtype detection (int32 vs int64) ----------------
__global__ __launch_bounds__(64) void detect_k(const int* __restrict__ e32, int* __restrict__ flag){
    int lane = threadIdx.x;
    int v = e32[2*lane + 1];                 // high word if int64, else a src value
    unsigned long long b = __ballot(v != 0);
    if(lane == 0) flag[0] = (b == 0ULL) ? 1 : 0;   // 1 => int64 layout
}

__device__ __forceinline__ int eidx(const int* __restrict__ e32, int f, int i){
    return f ? e32[2*(size_t)i] : e32[i];
}

// ---------------- pass A: per-bin edge counts (LDS histogram) ----------------
__global__ __launch_bounds__(256) void binA_k(const int* __restrict__ e32, const int* __restrict__ flag,
                                              int* __restrict__ binCnt){
    __shared__ int h[NBIN];
    for(int t = threadIdx.x; t < NBIN; t += 256) h[t] = 0;
    __syncthreads();
    int f = flag[0];
    int base = blockIdx.x * 2048;
    #pragma unroll
    for(int k = 0; k < 8; ++k){
        int i = base + k*256 + threadIdx.x;
        if(i < NE){
            int d = eidx(e32, f, NE + i);
            atomicAdd(&h[d / RBIN], 1);
        }
    }
    __syncthreads();
    for(int t = threadIdx.x; t < NBIN; t += 256){
        int v = h[t];
        if(v) atomicAdd(&binCnt[t*PAD], v);
    }
}

// ---------------- pass B: scan bin counts -> bin offsets (= coarse CSR offsets) ----------------
__global__ __launch_bounds__(512) void binB_k(const int* __restrict__ binCnt, int* __restrict__ binOff,
                                              int* __restrict__ binCur, int* __restrict__ rp){
    __shared__ int s[NBIN];
    int t = threadIdx.x;
    int v = binCnt[t*PAD];
    s[t] = v; __syncthreads();
    for(int off = 1; off < NBIN; off <<= 1){
        int u = (t >= off) ? s[t - off] : 0;
        __syncthreads();
        s[t] += u;
        __syncthreads();
    }
    int e = s[t] - v;          // exclusive
    binOff[t] = e;
    binCur[t*PAD] = e;
    if(t == NBIN-1){ binOff[NBIN] = NE; rp[NN] = NE; }
}

// ---------------- pass C: block-level multi-split scatter of (src,dst) into dst-bins ----------------
__global__ __launch_bounds__(256) void binC_k(const int* __restrict__ e32, const int* __restrict__ flag,
                                              int* __restrict__ binCur, int2* __restrict__ bins){
    __shared__ int2 ST[EPB];          // 32KB staged edges, grouped by bin
    __shared__ int hist[NBIN];
    __shared__ int lstart[NBIN];
    __shared__ int gbase[NBIN];
    __shared__ int cur[NBIN];
    const int t = threadIdx.x;
    const int e0 = blockIdx.x * EPB;
    const int n = min(EPB, NE - e0);
    const int f = flag[0];

    for(int b = t; b < NBIN; b += 256){ hist[b] = 0; cur[b] = 0; }
    __syncthreads();

    // load edges to registers + LDS histogram
    int2 ed[EPT];
    #pragma unroll
    for(int k = 0; k < EPT; ++k){
        int i = k*256 + t;
        if(i < n){
            ed[k].x = eidx(e32, f, e0 + i);
            ed[k].y = eidx(e32, f, NE + e0 + i);
            atomicAdd(&hist[ed[k].y / RBIN], 1);
        }
    }
    __syncthreads();

    // single-wave exclusive scan of 512 bins (8 serial bins/lane + wave scan)
    if(t < 64){
        int b0 = t*8;
        int pre[8]; int run = 0;
        #pragma unroll
        for(int i = 0; i < 8; ++i){ pre[i] = run; run += hist[b0 + i]; }
        int inc = run;
        for(int o = 1; o < 64; o <<= 1){
            int u = __shfl_up(inc, o, 64);
            if(t >= o) inc += u;
        }
        int excl = inc - run;
        #pragma unroll
        for(int i = 0; i < 8; ++i) lstart[b0 + i] = excl + pre[i];
    }
    // reserve contiguous global ranges (one atomic per bin per block)
    for(int b = t; b < NBIN; b += 256) gbase[b] = atomicAdd(&binCur[b*PAD], hist[b]);
    __syncthreads();

    // scatter into LDS grouped by bin
    #pragma unroll
    for(int k = 0; k < EPT; ++k){
        int i = k*256 + t;
        if(i < n){
            int b = ed[k].y / RBIN;
            int lo = atomicAdd(&cur[b], 1);
            ST[lstart[b] + lo] = ed[k];
        }
    }
    __syncthreads();

    // linear copy-out: consecutive staged entries in a bin -> consecutive global slots
    for(int i = t; i < n; i += 256){
        int2 e = ST[i];
        int b = e.y / RBIN;
        bins[gbase[b] + (i - lstart[b])] = e;
    }
}

// ---------------- pass D: per-bin CSR build (rp, dinv, csr_src) ----------------
__global__ __launch_bounds__(256) void binD_k(const int2* __restrict__ bins, const int* __restrict__ binOff,
                                              int* __restrict__ rp, float* __restrict__ dinv,
                                              int* __restrict__ csr_src){
    __shared__ int2 ES[CAP];
    __shared__ int hist[256];
    __shared__ int sc[256];
    __shared__ int cur[256];
    const int b = blockIdx.x;
    const int nbase = b * RBIN;
    if(nbase >= NN) return;                      // empty trailing bin
    const int nend = min(nbase + RBIN, NN);
    const int nr = nend - nbase;
    const int off0 = binOff[b];
    const int cnt  = binOff[b+1] - off0;
    const int t = threadIdx.x;
    hist[t] = 0; cur[t] = 0;
    __syncthreads();

    const bool single = (cnt <= CAP);
    // histogram phase
    for(int c0 = 0; c0 < cnt; c0 += CAP){
        int n = min(CAP, cnt - c0);
        for(int i = t; i < n; i += 256) ES[i] = bins[off0 + c0 + i];
        __syncthreads();
        for(int i = t; i < n; i += 256) atomicAdd(&hist[ES[i].y - nbase], 1);
        __syncthreads();
    }
    // exclusive scan of hist into sc
    int v = hist[t];
    sc[t] = v; __syncthreads();
    for(int off = 1; off < 256; off <<= 1){
        int u = (t >= off) ? sc[t - off] : 0;
        __syncthreads();
        sc[t] += u;
        __syncthreads();
    }
    int excl = sc[t] - v;
    sc[t] = excl;
    if(t < nr){
        rp[nbase + t]   = off0 + excl;
        dinv[nbase + t] = rsqrtf((float)(v + 1));   // +1 = self loop
    }
    __syncthreads();
    // scatter phase (ES still valid if single chunk)
    for(int c0 = 0; c0 < cnt; c0 += CAP){
        int n = min(CAP, cnt - c0);
        if(!single){
            for(int i = t; i < n; i += 256) ES[i] = bins[off0 + c0 + i];
            __syncthreads();
        }
        for(int i = t; i < n; i += 256){
            int dl = ES[i].y - nbase;
            int p = atomicAdd(&cur[dl], 1);
            csr_src[off0 + sc[dl] + p] = ES[i].x;
        }
        if(!single) __syncthreads();
    }
}

// ---------------- dense GEMM: out[row] = fp16( (A@W)[row] * dinv[row] ); optional relu on input ----------------
template<int K, int NC, bool RELU>
__global__ __launch_bounds__(256) void gemm_k(const float* __restrict__ A, const float* __restrict__ W,
                                              const float* __restrict__ dinv,
                                              __half* __restrict__ out, int M){
    constexpr int CH = K/4;          // float4 chunks per row
    constexpr int CMASK = CH - 1;
    __shared__ float Xs[64*K];
    __shared__ float Ws[K*NC];
    const int tid  = threadIdx.x;
    const int base = blockIdx.x * 64;

    for(int idx = tid; idx < K*NC; idx += 256) Ws[idx] = W[idx];

    for(int idx = tid; idx < 64*K; idx += 256){
        int r = idx / K;
        int k = idx % K;
        int row = base + r; if(row >= M) row = M - 1;
        float v = A[(size_t)row*K + k];
        if(RELU) v = fmaxf(v, 0.0f);
        int sw = ((k >> 2) + r) & CMASK;           // rotate-swizzle chunks to avoid bank conflicts
        Xs[r*K + (sw << 2) + (k & 3)] = v;
    }
    __syncthreads();

    const int tx = tid & 15, ty = tid >> 4;
    const int c0 = tx * 4;
    float acc[4][4] = {};
    if(c0 < NC){
        for(int k4 = 0; k4 < CH; ++k4){
            float4 xs[4];
            #pragma unroll
            for(int i = 0; i < 4; ++i){
                int r = ty*4 + i;
                int sw = (k4 + r) & CMASK;
                xs[i] = *(const float4*)&Xs[r*K + (sw << 2)];
            }
            float4 wsv[4];
            #pragma unroll
            for(int kk = 0; kk < 4; ++kk) wsv[kk] = *(const float4*)&Ws[(k4*4 + kk)*NC + c0];
            #pragma unroll
            for(int kk = 0; kk < 4; ++kk){
                const float* wp = (const float*)&wsv[kk];
                #pragma unroll
                for(int i = 0; i < 4; ++i){
                    float xv = ((const float*)&xs[i])[kk];
                    #pragma unroll
                    for(int j = 0; j < 4; ++j) acc[i][j] += xv * wp[j];
                }
            }
        }
    }
    #pragma unroll
    for(int i = 0; i < 4; ++i){
        int row = base + ty*4 + i;
        if(row < M && c0 < NC){
            float dv = dinv[row];
            __half2 h01 = __floats2half2_rn(acc[i][0]*dv, acc[i][1]*dv);
            __half2 h23 = __floats2half2_rn(acc[i][2]*dv, acc[i][3]*dv);
            __half2* dst = (__half2*)&out[(size_t)row*NC + c0];
            dst[0] = h01;
            dst[1] = h23;
        }
    }
}

// ---------------- CSR aggregation: 16 lanes/edge (half4 each), 4 edges per wave-instruction ----------------
// G[v] = b + dinv[v] * (sum_{s in N(v)} P[s] + P[v]) ; P fp16 pre-scaled by dinv. fp32 accum.
__device__ __forceinline__ float4 loadP4(const __half* __restrict__ P, size_t off){
    const __half2* p = (const __half2*)(P + off);
    __half2 a = p[0], b = p[1];
    float2 fa = __half22float2(a), fb = __half22float2(b);
    return make_float4(fa.x, fa.y, fb.x, fb.y);
}

template<int F, bool LSM>
__global__ __launch_bounds__(256) void agg_k(const __half* __restrict__ P, const int* __restrict__ rp,
                                             const int* __restrict__ csr_src,
                                             const float* __restrict__ dinv, const float* __restrict__ bias,
                                             float* __restrict__ G){
    constexpr int NQ = F/4;                       // active channel-quads per row (16 or 10)
    const int lane = threadIdx.x & 63;
    const int v = (blockIdx.x*256 + threadIdx.x) >> 6;
    if(v >= NN) return;
    const int g = lane >> 4;                      // edge-group 0..3
    const int q = lane & 15;                      // channel-quad
    const bool qa = (q < NQ);

    const int beg = rp[v], end = rp[v + 1];
    float4 acc = make_float4(0.f, 0.f, 0.f, 0.f);
    if(g == 0 && qa) acc = loadP4(P, (size_t)v*F + q*4);     // self-loop term

    int j = beg;
    #pragma unroll 1
    for(; j + 8 <= end; j += 8){
        int s0 = csr_src[j + g];
        int s1 = csr_src[j + 4 + g];
        if(qa){
            float4 h0 = loadP4(P, (size_t)s0*F + q*4);
            float4 h1 = loadP4(P, (size_t)s1*F + q*4);
            acc.x += h0.x + h1.x; acc.y += h0.y + h1.y;
            acc.z += h0.z + h1.z; acc.w += h0.w + h1.w;
        }
    }
    if(j + 4 <= end){
        int s0 = csr_src[j + g];
        if(qa){
            float4 h0 = loadP4(P, (size_t)s0*F + q*4);
            acc.x += h0.x; acc.y += h0.y; acc.z += h0.z; acc.w += h0.w;
        }
        j += 4;
    }
    const int rem = end - j;                      // 0..3
    if(g < rem){
        int s0 = csr_src[j + g];
        if(qa){
            float4 h0 = loadP4(P, (size_t)s0*F + q*4);
            acc.x += h0.x; acc.y += h0.y; acc.z += h0.z; acc.w += h0.w;
        }
    }

    // reduce across the 4 edge-groups (butterfly over lane bits 4,5)
    #pragma unroll
    for(int m = 16; m <= 32; m <<= 1){
        acc.x += __shfl_xor(acc.x, m, 64);
        acc.y += __shfl_xor(acc.y, m, 64);
        acc.z += __shfl_xor(acc.z, m, 64);
        acc.w += __shfl_xor(acc.w, m, 64);
    }

    float4 r;
    const float d = dinv[v];
    if(g == 0 && qa){
        float4 bb = *(const float4*)&bias[q*4];
        r.x = fmaf(acc.x, d, bb.x);
        r.y = fmaf(acc.y, d, bb.y);
        r.z = fmaf(acc.z, d, bb.z);
        r.w = fmaf(acc.w, d, bb.w);
        if(!LSM) *(float4*)&G[(size_t)v*F + q*4] = r;
    }
    if(LSM){
        // butterfly over lane bits 0..3 stays within each 16-lane group; group 0 is authoritative
        float lm = (g == 0 && qa) ? fmaxf(fmaxf(r.x, r.y), fmaxf(r.z, r.w)) : -3.402823466e38f;
        #pragma unroll
        for(int m = 1; m <= 8; m <<= 1) lm = fmaxf(lm, __shfl_xor(lm, m, 64));
        float ls = (g == 0 && qa)
                 ? (__expf(r.x - lm) + __expf(r.y - lm) + __expf(r.z - lm) + __expf(r.w - lm)) : 0.0f;
        #pragma unroll
        for(int m = 1; m <= 8; m <<= 1) ls += __shfl_xor(ls, m, 64);
        if(g == 0 && qa){
            float lz = lm + __logf(ls);
            r.x -= lz; r.y -= lz; r.z -= lz; r.w -= lz;
            *(float4*)&G[(size_t)v*F + q*4] = r;
        }
    }
}

extern "C" void kernel_launch(void* const* d_in, const int* in_sizes, int n_in,
                              void* d_out, int out_size, void* d_ws, size_t ws_size,
                              hipStream_t stream){
    const float* x   = (const float*)d_in[0];
    const int*   e32 = (const int*)  d_in[1];
    const float* W1  = (const float*)d_in[2];
    const float* b1  = (const float*)d_in[3];
    const float* W2  = (const float*)d_in[4];
    const float* b2  = (const float*)d_in[5];
    const float* W3  = (const float*)d_in[6];
    const float* b3  = (const float*)d_in[7];
    float* out = (float*)d_out;

    char* ws = (char*)d_ws;
    size_t off = 0;
    auto alloc = [&](size_t bytes) -> void* {
        void* p = ws + off;
        off = (off + bytes + 255) & ~(size_t)255;
        return p;
    };
    int*    rp     = (int*)   alloc((size_t)(NN+1)*4);
    int*    binCnt = (int*)   alloc((size_t)NBIN*PAD*4);
    int*    binOff = (int*)   alloc((size_t)(NBIN+1)*4);
    int*    binCur = (int*)   alloc((size_t)NBIN*PAD*4);
    int*    flag   = (int*)   alloc(256);
    float*  dinv   = (float*) alloc((size_t)NN*4);
    int*    csr_s  = (int*)   alloc((size_t)NE*4);
    __half* ph     = (__half*)alloc((size_t)NN*64*2);   // fp16 message matrix P
    float*  gA     = (float*) alloc((size_t)NN*64*4);
    float*  gB     = (float*) alloc((size_t)NN*64*4);
    int2*   bins   = (int2*)  gA;    // bins dead before agg1 writes gA

    hipMemsetAsync(binCnt, 0, (size_t)NBIN*PAD*4, stream);
    detect_k<<<1, 64, 0, stream>>>(e32, flag);
    binA_k<<<(NE + 2047)/2048, 256, 0, stream>>>(e32, flag, binCnt);
    binB_k<<<1, 512, 0, stream>>>(binCnt, binOff, binCur, rp);
    binC_k<<<(NE + EPB - 1)/EPB, 256, 0, stream>>>(e32, flag, binCur, bins);
    binD_k<<<NBIN, 256, 0, stream>>>(bins, binOff, rp, dinv, csr_s);

    const int GEMM_GRID = (NN + 63)/64;       // 1563
    const int AGG_GRID  = (NN*64 + 255)/256;  // 25000

    gemm_k<128,64,false><<<GEMM_GRID, 256, 0, stream>>>(x,  W1, dinv, ph, NN);
    agg_k<64,false><<<AGG_GRID, 256, 0, stream>>>(ph, rp, csr_s, dinv, b1, gA);
    gemm_k<64,64,true><<<GEMM_GRID, 256, 0, stream>>>(gA, W2, dinv, ph, NN);
    agg_k<64,false><<<AGG_GRID, 256, 0, stream>>>(ph, rp, csr_s, dinv, b2, gB);
    gemm_k<64,40,true><<<GEMM_GRID, 256, 0, stream>>>(gB, W3, dinv, ph, NN);
    agg_k<40,true><<<AGG_GRID, 256, 0, stream>>>(ph, rp, csr_s, dinv, b3, out);
}

// Round 7
// 270.378 us; speedup vs baseline: 2.3220x; 1.0391x over previous
//
#include <hip/hip_runtime.h>
#include <hip/hip_fp16.h>

#define NN 100000
#define NE 1250000
#define NBIN 512
#define RBIN 196          // ceil(NN/NBIN); bin b covers nodes [b*196, b*196+196)
#define PAD 16            // counter padding: 16 ints = 64B line
#define CAP 4096          // binD LDS edge-staging capacity (int2 = 32KB)
#define EPB 4096          // binC edges per block
#define EPT 16            // EPB/256

// ---------------- edge dtype detection (int32 vs int64) ----------------
__global__ __launch_bounds__(64) void detect_k(const int* __restrict__ e32, int* __restrict__ flag){
    int lane = threadIdx.x;
    int v = e32[2*lane + 1];                 // high word if int64, else a src value
    unsigned long long b = __ballot(v != 0);
    if(lane == 0) flag[0] = (b == 0ULL) ? 1 : 0;   // 1 => int64 layout
}

__device__ __forceinline__ int eidx(const int* __restrict__ e32, int f, int i){
    return f ? e32[2*(size_t)i] : e32[i];
}

// ---------------- pass A: per-bin edge counts (LDS histogram) ----------------
__global__ __launch_bounds__(256) void binA_k(const int* __restrict__ e32, const int* __restrict__ flag,
                                              int* __restrict__ binCnt){
    __shared__ int h[NBIN];
    for(int t = threadIdx.x; t < NBIN; t += 256) h[t] = 0;
    __syncthreads();
    int f = flag[0];
    int base = blockIdx.x * 2048;
    #pragma unroll
    for(int k = 0; k < 8; ++k){
        int i = base + k*256 + threadIdx.x;
        if(i < NE){
            int d = eidx(e32, f, NE + i);
            atomicAdd(&h[d / RBIN], 1);
        }
    }
    __syncthreads();
    for(int t = threadIdx.x; t < NBIN; t += 256){
        int v = h[t];
        if(v) atomicAdd(&binCnt[t*PAD], v);
    }
}

// ---------------- pass B: scan bin counts -> bin offsets (= coarse CSR offsets) ----------------
__global__ __launch_bounds__(512) void binB_k(const int* __restrict__ binCnt, int* __restrict__ binOff,
                                              int* __restrict__ binCur, int* __restrict__ rp){
    __shared__ int s[NBIN];
    int t = threadIdx.x;
    int v = binCnt[t*PAD];
    s[t] = v; __syncthreads();
    for(int off = 1; off < NBIN; off <<= 1){
        int u = (t >= off) ? s[t - off] : 0;
        __syncthreads();
        s[t] += u;
        __syncthreads();
    }
    int e = s[t] - v;          // exclusive
    binOff[t] = e;
    binCur[t*PAD] = e;
    if(t == NBIN-1){ binOff[NBIN] = NE; rp[NN] = NE; }
}

// ---------------- pass C: block-level multi-split scatter of (src,dst) into dst-bins ----------------
__global__ __launch_bounds__(256) void binC_k(const int* __restrict__ e32, const int* __restrict__ flag,
                                              int* __restrict__ binCur, int2* __restrict__ bins){
    __shared__ int2 ST[EPB];          // 32KB staged edges, grouped by bin
    __shared__ int hist[NBIN];
    __shared__ int lstart[NBIN];
    __shared__ int gbase[NBIN];
    __shared__ int cur[NBIN];
    const int t = threadIdx.x;
    const int e0 = blockIdx.x * EPB;
    const int n = min(EPB, NE - e0);
    const int f = flag[0];

    for(int b = t; b < NBIN; b += 256){ hist[b] = 0; cur[b] = 0; }
    __syncthreads();

    // load edges to registers + LDS histogram
    int2 ed[EPT];
    #pragma unroll
    for(int k = 0; k < EPT; ++k){
        int i = k*256 + t;
        if(i < n){
            ed[k].x = eidx(e32, f, e0 + i);
            ed[k].y = eidx(e32, f, NE + e0 + i);
            atomicAdd(&hist[ed[k].y / RBIN], 1);
        }
    }
    __syncthreads();

    // single-wave exclusive scan of 512 bins (8 serial bins/lane + wave scan)
    if(t < 64){
        int b0 = t*8;
        int pre[8]; int run = 0;
        #pragma unroll
        for(int i = 0; i < 8; ++i){ pre[i] = run; run += hist[b0 + i]; }
        int inc = run;
        for(int o = 1; o < 64; o <<= 1){
            int u = __shfl_up(inc, o, 64);
            if(t >= o) inc += u;
        }
        int excl = inc - run;
        #pragma unroll
        for(int i = 0; i < 8; ++i) lstart[b0 + i] = excl + pre[i];
    }
    // reserve contiguous global ranges (one atomic per bin per block)
    for(int b = t; b < NBIN; b += 256) gbase[b] = atomicAdd(&binCur[b*PAD], hist[b]);
    __syncthreads();

    // scatter into LDS grouped by bin
    #pragma unroll
    for(int k = 0; k < EPT; ++k){
        int i = k*256 + t;
        if(i < n){
            int b = ed[k].y / RBIN;
            int lo = atomicAdd(&cur[b], 1);
            ST[lstart[b] + lo] = ed[k];
        }
    }
    __syncthreads();

    // linear copy-out: consecutive staged entries in a bin -> consecutive global slots
    for(int i = t; i < n; i += 256){
        int2 e = ST[i];
        int b = e.y / RBIN;
        bins[gbase[b] + (i - lstart[b])] = e;
    }
}

// ---------------- pass D: per-bin CSR build (rp, dinv, csr_src) ----------------
__global__ __launch_bounds__(256) void binD_k(const int2* __restrict__ bins, const int* __restrict__ binOff,
                                              int* __restrict__ rp, float* __restrict__ dinv,
                                              int* __restrict__ csr_src){
    __shared__ int2 ES[CAP];
    __shared__ int hist[256];
    __shared__ int sc[256];
    __shared__ int cur[256];
    const int b = blockIdx.x;
    const int nbase = b * RBIN;
    if(nbase >= NN) return;                      // empty trailing bin
    const int nend = min(nbase + RBIN, NN);
    const int nr = nend - nbase;
    const int off0 = binOff[b];
    const int cnt  = binOff[b+1] - off0;
    const int t = threadIdx.x;
    hist[t] = 0; cur[t] = 0;
    __syncthreads();

    const bool single = (cnt <= CAP);
    // histogram phase
    for(int c0 = 0; c0 < cnt; c0 += CAP){
        int n = min(CAP, cnt - c0);
        for(int i = t; i < n; i += 256) ES[i] = bins[off0 + c0 + i];
        __syncthreads();
        for(int i = t; i < n; i += 256) atomicAdd(&hist[ES[i].y - nbase], 1);
        __syncthreads();
    }
    // exclusive scan of hist into sc
    int v = hist[t];
    sc[t] = v; __syncthreads();
    for(int off = 1; off < 256; off <<= 1){
        int u = (t >= off) ? sc[t - off] : 0;
        __syncthreads();
        sc[t] += u;
        __syncthreads();
    }
    int excl = sc[t] - v;
    sc[t] = excl;
    if(t < nr){
        rp[nbase + t]   = off0 + excl;
        dinv[nbase + t] = rsqrtf((float)(v + 1));   // +1 = self loop
    }
    __syncthreads();
    // scatter phase (ES still valid if single chunk)
    for(int c0 = 0; c0 < cnt; c0 += CAP){
        int n = min(CAP, cnt - c0);
        if(!single){
            for(int i = t; i < n; i += 256) ES[i] = bins[off0 + c0 + i];
            __syncthreads();
        }
        for(int i = t; i < n; i += 256){
            int dl = ES[i].y - nbase;
            int p = atomicAdd(&cur[dl], 1);
            csr_src[off0 + sc[dl] + p] = ES[i].x;
        }
        if(!single) __syncthreads();
    }
}

// ---------------- dense GEMM: out[row] = fp16( (A@W)[row] * dinv[row] ); optional relu on input ----------------
template<int K, int NC, bool RELU>
__global__ __launch_bounds__(256) void gemm_k(const float* __restrict__ A, const float* __restrict__ W,
                                              const float* __restrict__ dinv,
                                              __half* __restrict__ out, int M){
    constexpr int CH = K/4;          // float4 chunks per row
    constexpr int CMASK = CH - 1;
    __shared__ float Xs[64*K];
    __shared__ float Ws[K*NC];
    const int tid  = threadIdx.x;
    const int base = blockIdx.x * 64;

    // Ws staging: float4
    {
        const float4* Wv = (const float4*)W;
        float4* Wsv = (float4*)Ws;
        #pragma unroll 4
        for(int i = tid; i < K*NC/4; i += 256) Wsv[i] = Wv[i];
    }
    // Xs staging: float4, chunk-rotate swizzle
    {
        const int ch = tid & (CH - 1);
        const int r0 = tid / CH;
        constexpr int RSTEP = 256 / CH;
        #pragma unroll
        for(int r = r0; r < 64; r += RSTEP){
            int row = base + r; if(row >= M) row = M - 1;
            float4 v = *(const float4*)&A[(size_t)row*K + ch*4];
            if(RELU){ v.x=fmaxf(v.x,0.f); v.y=fmaxf(v.y,0.f); v.z=fmaxf(v.z,0.f); v.w=fmaxf(v.w,0.f); }
            int sw = (ch + r) & CMASK;
            *(float4*)&Xs[r*K + sw*4] = v;
        }
    }
    __syncthreads();

    const int tx = tid & 15, ty = tid >> 4;
    const int c0 = tx * 4;
    float acc[4][4] = {};
    if(c0 < NC){
        for(int k4 = 0; k4 < CH; ++k4){
            float4 xs[4];
            #pragma unroll
            for(int i = 0; i < 4; ++i){
                int r = ty*4 + i;
                int sw = (k4 + r) & CMASK;
                xs[i] = *(const float4*)&Xs[r*K + (sw << 2)];
            }
            float4 wsv[4];
            #pragma unroll
            for(int kk = 0; kk < 4; ++kk) wsv[kk] = *(const float4*)&Ws[(k4*4 + kk)*NC + c0];
            #pragma unroll
            for(int kk = 0; kk < 4; ++kk){
                const float* wp = (const float*)&wsv[kk];
                #pragma unroll
                for(int i = 0; i < 4; ++i){
                    float xv = ((const float*)&xs[i])[kk];
                    #pragma unroll
                    for(int j = 0; j < 4; ++j) acc[i][j] += xv * wp[j];
                }
            }
        }
    }
    #pragma unroll
    for(int i = 0; i < 4; ++i){
        int row = base + ty*4 + i;
        if(row < M && c0 < NC){
            float dv = dinv[row];
            __half2 h01 = __floats2half2_rn(acc[i][0]*dv, acc[i][1]*dv);
            __half2 h23 = __floats2half2_rn(acc[i][2]*dv, acc[i][3]*dv);
            __half2* dst = (__half2*)&out[(size_t)row*NC + c0];
            dst[0] = h01;
            dst[1] = h23;
        }
    }
}

// ---------------- CSR aggregation: 16 lanes/edge (half4 each), 4 edges per wave-instruction ----------------
// G[v] = b + dinv[v]*(sum P[s] + P[v]); P fp16 pre-scaled by dinv; fp32 accum (pairwise fp16 pre-add).
// 32-bit half2 indexing; loop lanes unguarded (garbage lanes masked at epilogue).
template<int F, bool LSM>
__global__ __launch_bounds__(256) void agg_k(const __half* __restrict__ P, const int* __restrict__ rp,
                                             const int* __restrict__ csr_src,
                                             const float* __restrict__ dinv, const float* __restrict__ bias,
                                             float* __restrict__ G){
    constexpr int NQ = F/4;                       // active channel-quads (16 or 10)
    constexpr unsigned F2 = F/2;                  // half2 per row
    const int lane = threadIdx.x & 63;
    const int v = (blockIdx.x*256 + threadIdx.x) >> 6;
    if(v >= NN) return;
    const int g = lane >> 4;                      // edge-group 0..3
    const int q = lane & 15;                      // channel-quad
    const bool qa = (q < NQ);
    const unsigned qo = (unsigned)q*2;
    const __half2* __restrict__ P2 = (const __half2*)P;

    const int beg = rp[v], end = rp[v + 1];
    float4 acc = make_float4(0.f, 0.f, 0.f, 0.f);
    if(g == 0 && qa){                             // self-loop term
        __half2 a = P2[(unsigned)v*F2 + qo], b = P2[(unsigned)v*F2 + qo + 1];
        float2 fa = __half22float2(a), fb = __half22float2(b);
        acc = make_float4(fa.x, fa.y, fb.x, fb.y);
    }

    int j = beg;
    #pragma unroll 1
    for(; j + 16 <= end; j += 16){
        unsigned i0 = (unsigned)csr_src[j + g]     *F2 + qo;
        unsigned i1 = (unsigned)csr_src[j + 4 + g] *F2 + qo;
        unsigned i2 = (unsigned)csr_src[j + 8 + g] *F2 + qo;
        unsigned i3 = (unsigned)csr_src[j + 12 + g]*F2 + qo;
        __half2 a0 = P2[i0], b0 = P2[i0+1];
        __half2 a1 = P2[i1], b1 = P2[i1+1];
        __half2 a2 = P2[i2], b2 = P2[i2+1];
        __half2 a3 = P2[i3], b3 = P2[i3+1];
        __half2 sa = __hadd2(a0, a1), sb = __hadd2(b0, b1);
        __half2 ta = __hadd2(a2, a3), tb = __hadd2(b2, b3);
        float2 f0 = __half22float2(sa), f1 = __half22float2(sb);
        float2 f2 = __half22float2(ta), f3 = __half22float2(tb);
        acc.x += f0.x + f2.x; acc.y += f0.y + f2.y;
        acc.z += f1.x + f3.x; acc.w += f1.y + f3.y;
    }
    if(j + 8 <= end){
        unsigned i0 = (unsigned)csr_src[j + g]    *F2 + qo;
        unsigned i1 = (unsigned)csr_src[j + 4 + g]*F2 + qo;
        __half2 a0 = P2[i0], b0 = P2[i0+1];
        __half2 a1 = P2[i1], b1 = P2[i1+1];
        __half2 sa = __hadd2(a0, a1), sb = __hadd2(b0, b1);
        float2 f0 = __half22float2(sa), f1 = __half22float2(sb);
        acc.x += f0.x; acc.y += f0.y; acc.z += f1.x; acc.w += f1.y;
        j += 8;
    }
    if(j + 4 <= end){
        unsigned i0 = (unsigned)csr_src[j + g]*F2 + qo;
        __half2 a = P2[i0], b = P2[i0+1];
        float2 fa = __half22float2(a), fb = __half22float2(b);
        acc.x += fa.x; acc.y += fa.y; acc.z += fb.x; acc.w += fb.y;
        j += 4;
    }
    const int rem = end - j;                      // 0..3
    if(g < rem){
        unsigned i0 = (unsigned)csr_src[j + g]*F2 + qo;
        __half2 a = P2[i0], b = P2[i0+1];
        float2 fa = __half22float2(a), fb = __half22float2(b);
        acc.x += fa.x; acc.y += fa.y; acc.z += fb.x; acc.w += fb.y;
    }

    // reduce across the 4 edge-groups (butterfly over lane bits 4,5)
    #pragma unroll
    for(int m = 16; m <= 32; m <<= 1){
        acc.x += __shfl_xor(acc.x, m, 64);
        acc.y += __shfl_xor(acc.y, m, 64);
        acc.z += __shfl_xor(acc.z, m, 64);
        acc.w += __shfl_xor(acc.w, m, 64);
    }

    float4 r;
    const float d = dinv[v];
    if(g == 0 && qa){
        float4 bb = *(const float4*)&bias[q*4];
        r.x = fmaf(acc.x, d, bb.x);
        r.y = fmaf(acc.y, d, bb.y);
        r.z = fmaf(acc.z, d, bb.z);
        r.w = fmaf(acc.w, d, bb.w);
        if(!LSM) *(float4*)&G[(size_t)v*F + q*4] = r;
    }
    if(LSM){
        float lm = (g == 0 && qa) ? fmaxf(fmaxf(r.x, r.y), fmaxf(r.z, r.w)) : -3.402823466e38f;
        #pragma unroll
        for(int m = 1; m <= 8; m <<= 1) lm = fmaxf(lm, __shfl_xor(lm, m, 64));
        float ls = (g == 0 && qa)
                 ? (__expf(r.x - lm) + __expf(r.y - lm) + __expf(r.z - lm) + __expf(r.w - lm)) : 0.0f;
        #pragma unroll
        for(int m = 1; m <= 8; m <<= 1) ls += __shfl_xor(ls, m, 64);
        if(g == 0 && qa){
            float lz = lm + __logf(ls);
            r.x -= lz; r.y -= lz; r.z -= lz; r.w -= lz;
            *(float4*)&G[(size_t)v*F + q*4] = r;
        }
    }
}

extern "C" void kernel_launch(void* const* d_in, const int* in_sizes, int n_in,
                              void* d_out, int out_size, void* d_ws, size_t ws_size,
                              hipStream_t stream){
    const float* x   = (const float*)d_in[0];
    const int*   e32 = (const int*)  d_in[1];
    const float* W1  = (const float*)d_in[2];
    const float* b1  = (const float*)d_in[3];
    const float* W2  = (const float*)d_in[4];
    const float* b2  = (const float*)d_in[5];
    const float* W3  = (const float*)d_in[6];
    const float* b3  = (const float*)d_in[7];
    float* out = (float*)d_out;

    char* ws = (char*)d_ws;
    size_t off = 0;
    auto alloc = [&](size_t bytes) -> void* {
        void* p = ws + off;
        off = (off + bytes + 255) & ~(size_t)255;
        return p;
    };
    int*    rp     = (int*)   alloc((size_t)(NN+1)*4);
    int*    binCnt = (int*)   alloc((size_t)NBIN*PAD*4);
    int*    binOff = (int*)   alloc((size_t)(NBIN+1)*4);
    int*    binCur = (int*)   alloc((size_t)NBIN*PAD*4);
    int*    flag   = (int*)   alloc(256);
    float*  dinv   = (float*) alloc((size_t)NN*4);
    int*    csr_s  = (int*)   alloc((size_t)NE*4);
    __half* ph     = (__half*)alloc((size_t)NN*64*2);   // fp16 message matrix P
    float*  gA     = (float*) alloc((size_t)NN*64*4);
    float*  gB     = (float*) alloc((size_t)NN*64*4);
    int2*   bins   = (int2*)  gA;    // bins dead before agg1 writes gA

    hipMemsetAsync(binCnt, 0, (size_t)NBIN*PAD*4, stream);
    detect_k<<<1, 64, 0, stream>>>(e32, flag);
    binA_k<<<(NE + 2047)/2048, 256, 0, stream>>>(e32, flag, binCnt);
    binB_k<<<1, 512, 0, stream>>>(binCnt, binOff, binCur, rp);
    binC_k<<<(NE + EPB - 1)/EPB, 256, 0, stream>>>(e32, flag, binCur, bins);
    binD_k<<<NBIN, 256, 0, stream>>>(bins, binOff, rp, dinv, csr_s);

    const int GEMM_GRID = (NN + 63)/64;       // 1563
    const int AGG_GRID  = (NN*64 + 255)/256;  // 25000

    gemm_k<128,64,false><<<GEMM_GRID, 256, 0, stream>>>(x,  W1, dinv, ph, NN);
    agg_k<64,false><<<AGG_GRID, 256, 0, stream>>>(ph, rp, csr_s, dinv, b1, gA);
    gemm_k<64,64,true><<<GEMM_GRID, 256, 0, stream>>>(gA, W2, dinv, ph, NN);
    agg_k<64,false><<<AGG_GRID, 256, 0, stream>>>(ph, rp, csr_s, dinv, b2, gB);
    gemm_k<64,40,true><<<GEMM_GRID, 256, 0, stream>>>(gB, W3, dinv, ph, NN);
    agg_k<40,true><<<AGG_GRID, 256, 0, stream>>>(ph, rp, csr_s, dinv, b3, out);
}